// Round 9
// baseline (535.896 us; speedup 1.0000x reference)
//
#include <hip/hip_runtime.h>
#include <hip/hip_cooperative_groups.h>
#include <math.h>

namespace cg = cooperative_groups;

typedef _Float16 h8 __attribute__((ext_vector_type(8)));
typedef float    f4v __attribute__((ext_vector_type(4)));

#define N_TRAIN 400000
#define DIMS    27
#define BQ      512
#define NCLS    11
#define KNN     3
#define NB      500            // blocks: 2/CU x 256 CU = 512 co-resident slots >= 500
#define P1T     1024           // threads (16 waves)
#define PTS_BLK 800            // points per block (500*800 = 400000 exact)
#define PTS_SUP 160            // points per super-tile
#define NSUP    5              // super-tiles per block
#define NPT     10             // ptiles per super-tile (tiles/block = 50, fits 6 bits)
#define RAWF    4320           // floats per super-tile (160*27)
#define TILE_B  2048           // conv bytes per ptile: hi 1024 + lo 1024
#define NC      (NB * KNN)     // candidates per query (1500)

#define U64MAX 0xFFFFFFFFFFFFFFFFULL

// lexicographic (key, idx) insert into ascending sorted triple — matches top_k ties
__device__ __forceinline__ void insert3(float d, int i, float* bd, int* bi) {
    if (d < bd[2] || (d == bd[2] && i < bi[2])) {
        if (d < bd[1] || (d == bd[1] && i < bi[1])) {
            bd[2] = bd[1]; bi[2] = bi[1];
            if (d < bd[0] || (d == bd[0] && i < bi[0])) {
                bd[1] = bd[0]; bi[1] = bi[0];
                bd[0] = d; bi[0] = i;
            } else { bd[1] = d; bi[1] = i; }
        } else { bd[2] = d; bi[2] = i; }
    }
}

// 64-bit xor-shuffle via two 32-bit shuffles
__device__ __forceinline__ unsigned long long shfl_xor_u64(unsigned long long v, int m) {
    unsigned lo = (unsigned)v, hi = (unsigned)(v >> 32);
    lo = __shfl_xor(lo, m, 64);
    hi = __shfl_xor(hi, m, 64);
    return ((unsigned long long)hi << 32) | lo;
}

// branchless insert into ascending sorted-3 of u64 (keep 3 smallest)
__device__ __forceinline__ void ins3u64(unsigned long long e,
                                        unsigned long long& t0,
                                        unsigned long long& t1,
                                        unsigned long long& t2) {
    unsigned long long a  = e < t2 ? e : t2;
    unsigned long long n2 = t1 > a ? t1 : a;
    unsigned long long n1 = t1 < a ? t1 : a;
    t2 = n2;
    unsigned long long m1 = t0 > n1 ? t0 : n1;
    t0 = t0 < n1 ? t0 : n1;
    t1 = m1;
}

// branchless compare-exchange (ascending)
#define CE(a, b) do { unsigned long long lo_ = (a) < (b) ? (a) : (b); \
                      unsigned long long hi_ = (a) < (b) ? (b) : (a); \
                      (a) = lo_; (b) = hi_; } while (0)

__device__ __forceinline__ void stage16(const float* g, float* l) {
    __builtin_amdgcn_global_load_lds((const __attribute__((address_space(1))) void*)g,
                                     (__attribute__((address_space(3))) void*)l, 16, 0, 0);
}

// ================= phase S: per-block max|row| over own 800 rows -> partial =================
// uint4 4-row groups (g*432 bytes, 16B aligned); column (4k+e)%27 is compile-time (rule #20).
__device__ __forceinline__ void phaseS(const float* __restrict__ train,
                                       float* __restrict__ partial,
                                       int bid, int tid, float* redS) {
    int lane = tid & 63, w = tid >> 6;
    float m[DIMS];
#pragma unroll
    for (int d = 0; d < DIMS; ++d) m[d] = 0.f;
    if (tid < PTS_BLK / 4) {                       // 200 groups of 4 rows
        int g = bid * (PTS_BLK / 4) + tid;
        const uint4* p = (const uint4*)(train + (size_t)g * (4 * DIMS));
#pragma unroll
        for (int k = 0; k < DIMS; ++k) {
            uint4 v = p[k];
            m[(4 * k + 0) % DIMS] = fmaxf(m[(4 * k + 0) % DIMS], fabsf(__uint_as_float(v.x)));
            m[(4 * k + 1) % DIMS] = fmaxf(m[(4 * k + 1) % DIMS], fabsf(__uint_as_float(v.y)));
            m[(4 * k + 2) % DIMS] = fmaxf(m[(4 * k + 2) % DIMS], fabsf(__uint_as_float(v.z)));
            m[(4 * k + 3) % DIMS] = fmaxf(m[(4 * k + 3) % DIMS], fabsf(__uint_as_float(v.w)));
        }
    }
    if (w < 4) {                                   // only waves 0..3 hold rows (200 < 256)
#pragma unroll
        for (int d = 0; d < DIMS; ++d) {           // wave butterfly (27 dims x 6 steps)
            float t = m[d];
#pragma unroll
            for (int st = 1; st < 64; st <<= 1) t = fmaxf(t, __shfl_xor(t, st, 64));
            m[d] = t;
        }
        if (lane == 0) {
#pragma unroll
            for (int d = 0; d < DIMS; ++d) redS[w * 32 + d] = m[d];
        }
    }
    __syncthreads();
    if (tid < 32) {
        float v = 0.f;
        if (tid < DIMS) {
#pragma unroll
            for (int g2 = 0; g2 < 4; ++g2) v = fmaxf(v, redS[g2 * 32 + tid]);
        }
        partial[bid * 32 + tid] = v;               // dims 27..31 = 0 (fully written, no memset)
    }
    __threadfence();
}

// reduce NB x 32 partials -> s_inv (exact same values as the old atomicMax path)
__device__ __forceinline__ void scale_reduce(const float* __restrict__ partial,
                                             float* redP, float* s_inv, int tid) {
    if (tid < 512) {
        int d = tid & 31, ch = tid >> 5;           // 16 chunks
        float v = 0.f;
        for (int b = ch; b < NB; b += 16) v = fmaxf(v, partial[b * 32 + d]);
        redP[ch * 32 + d] = v;
    }
    __syncthreads();
    if (tid < 32) {
        float sc = 0.f;
#pragma unroll
        for (int g2 = 0; g2 < 16; ++g2) sc = fmaxf(sc, redP[g2 * 32 + tid]);
        s_inv[tid] = (sc != 0.f) ? 1.f / sc : 0.f; // divide_no_nan; 0 for d>=27
    }
}

// conv: task = (point p, kblock gq of 8 dims); 640 tasks, waves 10..15 skip
__device__ __forceinline__ void conv_tile(const float* rw, unsigned char* dst0,
                                          int tid, const float* s_inv) {
    if (tid < PTS_SUP * 4) {
        int p = tid >> 2, gq = tid & 3;
        float x[8]; float part = 0.f;
#pragma unroll
        for (int i = 0; i < 8; ++i) {
            int d = gq * 8 + i;
            int dc = d < DIMS ? d : (DIMS - 1);    // clamp; s_inv[d>=27]=0 zeroes value
            float v = rw[p * DIMS + dc] * s_inv[d];
            x[i] = v;
            part = fmaf(v, v, part);
        }
        part += __shfl_xor(part, 1, 64);
        part += __shfl_xor(part, 2, 64);           // all 4 kblock-lanes hold xn
        h8 hv, lv;
#pragma unroll
        for (int i = 0; i < 8; ++i) {
            _Float16 h = (_Float16)x[i];
            hv[i] = h;
            lv[i] = (_Float16)(x[i] - (float)h);
        }
        if (gq == 3) {                             // slot i=3 is k=27: -xn/2 split
            float tt = -0.5f * part;
            _Float16 th = (_Float16)tt;
            hv[3] = th;
            lv[3] = (_Float16)(tt - (float)th);
        }
        unsigned char* dstb = dst0 + (p >> 4) * TILE_B + gq * 256 + (p & 15) * 16;
        *(h8*)dstb = hv;
        *(h8*)(dstb + 1024) = lv;
    }
}

// compute one super-tile: 10 ptiles x 2 query-tiles x 3 MFMA + u32 top-2 update (6-bit tile)
__device__ __forceinline__ void compute_super(const unsigned char* cb, int ss, int lane,
                                              const h8* bhi, const h8* blo,
                                              unsigned kb0[2][4], unsigned kb1[2][4]) {
    const f4v z4 = {64.f, 64.f, 64.f, 64.f};       // +64 bias rides through MFMA C
    for (int t = 0; t < NPT; ++t) {
        const unsigned char* basep = cb + t * TILE_B;
        h8 ahi = *(const h8*)(basep + lane * 16);  // lane-linear: conflict-free
        h8 alo = *(const h8*)(basep + 1024 + lane * 16);
        unsigned ic = 63u - (unsigned)(ss * NPT + t);   // wave-uniform tile code, 6 bits
#pragma unroll
        for (int j = 0; j < 2; ++j) {
            f4v acc;
            acc = __builtin_amdgcn_mfma_f32_16x16x32_f16(alo, bhi[j], z4, 0, 0, 0);
            acc = __builtin_amdgcn_mfma_f32_16x16x32_f16(ahi, blo[j], acc, 0, 0, 0);
            acc = __builtin_amdgcn_mfma_f32_16x16x32_f16(ahi, bhi[j], acc, 0, 0, 0);
#pragma unroll
            for (int r = 0; r < 4; ++r) {
                unsigned key = (__float_as_uint(acc[r]) & 0xFFFFFFC0u) | ic;  // v_and_or_b32
                unsigned b0 = kb0[j][r];
                unsigned m  = key < b0 ? key : b0;  // v_min_u32
                kb0[j][r]   = key > b0 ? key : b0;  // v_max_u32
                unsigned b1 = kb1[j][r];
                kb1[j][r]   = m > b1 ? m : b1;      // v_max_u32
            }
        }
    }
}

// ================= phase P1: staged/pipelined MFMA scan -> per-block top-3 per query =================
__device__ __forceinline__ void phaseP1(const float* __restrict__ train,
                                        const float* __restrict__ query,
                                        const float* __restrict__ partial,
                                        unsigned long long* __restrict__ cand,
                                        int bid, int tid,
                                        float* s_inv, float* rawb, unsigned char* convbb,
                                        float* redP) {
    int lane = tid & 63, w = tid >> 6;
    int l15 = lane & 15, quad = lane >> 4;
    int p0 = bid * PTS_BLK;
    const float* gsup = train + (size_t)p0 * DIMS; // 16B aligned (800*108 % 16 == 0)

    {   // stage super-tile 0 (async; flies during scale reduce)
        const float* gp = gsup; float* lp = rawb;
        stage16(gp + tid * 4, lp + tid * 4);
        if (tid < 56) stage16(gp + 4096 + tid * 4, lp + 4096 + tid * 4);
    }
    scale_reduce(partial, redP, s_inv, tid);       // internal barrier

    unsigned kb0[2][4], kb1[2][4];                 // top-2 keys per (j, r); 0 = -inf sentinel
#pragma unroll
    for (int j = 0; j < 2; ++j)
#pragma unroll
        for (int r = 0; r < 4; ++r) { kb0[j][r] = 0u; kb1[j][r] = 0u; }

    __syncthreads();   // barrier A: s_inv visible; raw[0] ready (vmcnt drained)

    {   // stage super-tile 1
        const float* gp = gsup + RAWF; float* lp = rawb + RAWF;
        stage16(gp + tid * 4, lp + tid * 4);
        if (tid < 56) stage16(gp + 4096 + tid * 4, lp + 4096 + tid * 4);
    }
    conv_tile(rawb, convbb, tid, s_inv);           // conv(0)

    h8 bhi[2], blo[2];                             // in-register qprep (same op order as verified)
#pragma unroll
    for (int j = 0; j < 2; ++j) {
        int q = (w * 2 + j) * 16 + l15;            // query 0..511
        const float* qr = query + (size_t)q * DIMS;
#pragma unroll
        for (int i = 0; i < 8; ++i) {
            int d = quad * 8 + i;
            int dc = d < DIMS ? d : (DIMS - 1);
            float xs = qr[dc] * s_inv[d];
            _Float16 hi = (_Float16)xs;
            _Float16 lo = (_Float16)(xs - (float)hi);
            bool is27 = (d == 27);
            bhi[j][i] = is27 ? (_Float16)1.f : hi; // k=27 slot multiplies A's -xn/2
            blo[j][i] = is27 ? (_Float16)0.f : lo;
        }
    }

    for (int s = 1; s < NSUP; ++s) {               // barrier, stage(s+1), conv(s), compute(s-1)
        __syncthreads();
        if (s + 1 < NSUP) {
            const float* gp = gsup + (size_t)(s + 1) * RAWF;
            float* lp = rawb + ((s + 1) & 1) * RAWF;
            stage16(gp + tid * 4, lp + tid * 4);
            if (tid < 56) stage16(gp + 4096 + tid * 4, lp + 4096 + tid * 4);
        }
        conv_tile(rawb + (s & 1) * RAWF, convbb + (s & 1) * (NPT * TILE_B), tid, s_inv);
        compute_super(convbb + ((s - 1) & 1) * (NPT * TILE_B), s - 1, lane, bhi, blo, kb0, kb1);
    }
    __syncthreads();
    compute_super(convbb + ((NSUP - 1) & 1) * (NPT * TILE_B), NSUP - 1, lane, bhi, blo, kb0, kb1);

    // decode + cross-quad merge -> block top-3 per query -> cand
    int qr4 = quad * 4;
#pragma unroll
    for (int j = 0; j < 2; ++j) {
        unsigned long long t0 = U64MAX, t1 = U64MAX, t2 = U64MAX;
#pragma unroll
        for (int r = 0; r < 4; ++r) {
#pragma unroll
            for (int h = 0; h < 2; ++h) {
                unsigned k = h ? kb1[j][r] : kb0[j][r];
                unsigned tile = 63u - (k & 63u);
                unsigned gi = (unsigned)(p0 + (int)tile * 16 + qr4 + r);
                unsigned long long e = ((unsigned long long)(~(k | 63u)) << 32) | gi;
                ins3u64(e, t0, t1, t2);
            }
        }
#pragma unroll
        for (int step = 16; step <= 32; step <<= 1) {
            unsigned long long o0 = shfl_xor_u64(t0, step);
            unsigned long long o1 = shfl_xor_u64(t1, step);
            unsigned long long o2 = shfl_xor_u64(t2, step);
            ins3u64(o0, t0, t1, t2);
            ins3u64(o1, t0, t1, t2);
            ins3u64(o2, t0, t1, t2);
        }
        if (quad == 0) {
            int qq = (w * 2 + j) * 16 + l15;
            size_t off = (size_t)qq * NC + (size_t)bid * KNN;
            cand[off + 0] = t0; cand[off + 1] = t1; cand[off + 2] = t2;
        }
    }
    __threadfence();
}

// ================= phase P2: u64 top-8 merge -> exact f32 refine -> vote =================
__device__ __forceinline__ void phaseP2(const unsigned long long* __restrict__ cand,
                                        const float* __restrict__ train,
                                        const float* __restrict__ query,
                                        const float* __restrict__ labels,
                                        float* __restrict__ out,
                                        int bid, int tid,
                                        const float* s_inv, unsigned long long* smerge) {
    int lane = tid & 63, w = tid >> 6;
    for (int q = bid; q < BQ; q += NB) {           // blocks 0..11 handle 2 queries, rest 1
        const unsigned long long* cd = cand + (size_t)q * NC;
        unsigned long long c0 = cd[tid];                                    // tid < 1500 always
        unsigned long long c1 = (tid + P1T < NC) ? cd[tid + P1T] : U64MAX;  // 476 threads
        CE(c0, c1);
#pragma unroll
        for (int k = 0; k < 8; ++k) {              // per-wave top-8 by butterfly-min extraction
            unsigned long long m = c0;
#pragma unroll
            for (int st = 1; st < 64; st <<= 1) {
                unsigned long long o = shfl_xor_u64(m, st);
                if (o < m) m = o;
            }
            if (lane == 0) smerge[w * 8 + k] = m;
            bool win = (c0 == m);                  // unique pop (distinct idx)
            c0 = win ? c1 : c0;
            c1 = win ? U64MAX : c1;
        }
        __syncthreads();

        if (w == 0) {
            // merge 128 wave winners -> global top-8; lane k keeps idx of rank k
            int myi = 0x7fffffff;
            unsigned long long e0 = smerge[lane], e1 = smerge[64 + lane];
            CE(e0, e1);
#pragma unroll
            for (int k = 0; k < 8; ++k) {
                unsigned long long m = e0;
#pragma unroll
                for (int st = 1; st < 64; st <<= 1) {
                    unsigned long long o = shfl_xor_u64(m, st);
                    if (o < m) m = o;
                }
                if (lane == k) myi = (int)(unsigned)m;
                bool win = (e0 == m);
                e0 = win ? e1 : e0;
                e1 = win ? U64MAX : e1;
            }

            // exact refine — same op order as the verified path
            float qn_ = 0.f;
#pragma unroll
            for (int d = 0; d < DIMS; ++d) {
                float v = query[(size_t)q * DIMS + d] * s_inv[d];
                qn_ = fmaf(v, v, qn_);
            }
            float myd2 = 3.4e38f;
            if (lane < 8) {
                const float* r = train + (size_t)myi * DIMS;
                float xnv = 0.f, dot = 0.f;
#pragma unroll
                for (int d = 0; d < DIMS; ++d) {
                    float iv = s_inv[d];
                    float qv = query[(size_t)q * DIMS + d] * iv;
                    float tv = r[d] * iv;
                    xnv = fmaf(tv, tv, xnv);
                    dot = fmaf(qv, tv, dot);
                }
                myd2 = fmaf(-2.f, dot, qn_ + xnv);
            }

            float bd[KNN] = {3.4e38f, 3.4e38f, 3.4e38f};
            int   bi[KNN] = {0x7fffffff, 0x7fffffff, 0x7fffffff};
#pragma unroll
            for (int k = 0; k < 8; ++k) {
                float dk = __shfl(myd2, k, 64);
                int   ik = __shfl(myi, k, 64);
                insert3(dk, ik, bd, bi);
            }

            if (lane == 0) {
                float kd[KNN];
#pragma unroll
                for (int k = 0; k < KNN; ++k) kd[k] = sqrtf(fmaxf(bd[k], 0.f));
                float votes[NCLS];
#pragma unroll
                for (int c = 0; c < NCLS; ++c) votes[c] = 0.f;
#pragma unroll
                for (int k = 0; k < KNN; ++k) {
                    float ks = (kd[k] == 0.f) ? 1.f : kd[k];
                    const float* lr = labels + (size_t)bi[k] * NCLS;
#pragma unroll
                    for (int c = 0; c < NCLS; ++c) votes[c] += lr[c] / ks;
                }
                int best = 0; float bv = votes[0];
#pragma unroll
                for (int c = 1; c < NCLS; ++c) { if (votes[c] > bv) { bv = votes[c]; best = c; } }
                bool zero_hit = (kd[0] == 0.f);
#pragma unroll
                for (int k = 0; k < KNN; ++k) out[(size_t)q * KNN + k] = kd[k];
                const float* l0 = labels + (size_t)bi[0] * NCLS;
                float* ro = out + (size_t)BQ * KNN + (size_t)q * NCLS;
#pragma unroll
                for (int c = 0; c < NCLS; ++c)
                    ro[c] = zero_hit ? l0[c] : ((c == best) ? 1.f : 0.f);
            }
        }
        __syncthreads();                           // smerge reuse guard between q iterations
    }
}

// ---------------- mega kernel (cooperative): S -> sync -> P1 -> sync -> P2 ----------------
// R8 ran cooperatively at 1 blk/CU (NB=250) and lost all barrier overlap (328us). This round
// restores the PROVEN 2-blk/CU geometry (NB=500, 8 waves/SIMD): R8's compiled VGPR=60 <= 64 and
// LDS 75776*2 <= 160K -> 512 co-resident slots >= 500. Occupancy-checked at launch w/ fallback.
__global__ __attribute__((amdgpu_flat_work_group_size(P1T, P1T)))
__attribute__((amdgpu_waves_per_eu(4)))
void k_mega(const float* __restrict__ train,
            const float* __restrict__ query,
            const float* __restrict__ labels,
            float* __restrict__ partial,
            unsigned long long* __restrict__ cand,
            float* __restrict__ out) {
    __shared__ float s_inv[32];
    __shared__ __align__(16) float raw[2][RAWF];                     // 34560 B
    __shared__ __align__(16) unsigned char convb[2][NPT * TILE_B];   // 40960 B
    // phase-local scratch aliased into convb (disjoint lifetimes, sync-separated):
    float* redS = (float*)&convb[0][0];                              // [4][32] phase S
    float* redP = (float*)&convb[0][4096];                           // [16][32] scale reduce
    unsigned long long* smerge = (unsigned long long*)&convb[0][8192]; // [128] phase P2

    int tid = threadIdx.x, bid = blockIdx.x;
    phaseS(train, partial, bid, tid, redS);
    cg::this_grid().sync();
    phaseP1(train, query, partial, cand, bid, tid, s_inv, &raw[0][0], &convb[0][0], redP);
    cg::this_grid().sync();
    phaseP2(cand, train, query, labels, out, bid, tid, s_inv, smerge);
}

// ---------------- non-cooperative fallback: same phases as 3 kernels ----------------
__global__ __attribute__((amdgpu_flat_work_group_size(P1T, P1T)))
void k_scale_f(const float* __restrict__ train, float* __restrict__ partial) {
    __shared__ float redS[4 * 32];
    phaseS(train, partial, blockIdx.x, threadIdx.x, redS);
}

__global__ __attribute__((amdgpu_flat_work_group_size(P1T, P1T)))
__attribute__((amdgpu_waves_per_eu(4)))
void k_p1_f(const float* __restrict__ train, const float* __restrict__ query,
            const float* __restrict__ partial, unsigned long long* __restrict__ cand) {
    __shared__ float s_inv[32];
    __shared__ __align__(16) float raw[2][RAWF];
    __shared__ __align__(16) unsigned char convb[2][NPT * TILE_B];
    float* redP = (float*)&convb[0][4096];
    phaseP1(train, query, partial, cand, blockIdx.x, threadIdx.x,
            s_inv, &raw[0][0], &convb[0][0], redP);
}

__global__ __attribute__((amdgpu_flat_work_group_size(P1T, P1T)))
void k_p2_f(const unsigned long long* __restrict__ cand, const float* __restrict__ train,
            const float* __restrict__ query, const float* __restrict__ labels,
            const float* __restrict__ partial, float* __restrict__ out) {
    __shared__ float s_inv[32];
    __shared__ float redP[512];
    __shared__ unsigned long long smerge[128];
    scale_reduce(partial, redP, s_inv, threadIdx.x);
    __syncthreads();
    phaseP2(cand, train, query, labels, out, blockIdx.x, threadIdx.x, s_inv, smerge);
}

extern "C" void kernel_launch(void* const* d_in, const int* in_sizes, int n_in,
                              void* d_out, int out_size, void* d_ws, size_t ws_size,
                              hipStream_t stream) {
    const float* query  = (const float*)d_in[0];
    const float* train  = (const float*)d_in[1];
    const float* labels = (const float*)d_in[2];
    float* out = (float*)d_out;

    // ws layout:
    //   [0)      partial: 500*32 f32 (64000 B, fully written -> no memset)
    //   [65536)  cand: 512*1500 u64 (6144000 B)
    char* ws = (char*)d_ws;
    float* partial = (float*)ws;
    unsigned long long* cand = (unsigned long long*)(ws + 65536);

    // decide cooperative viability once: need 2 blocks/CU so 500 blocks co-reside on 256 CUs
    static int coop_ok = -1;
    if (coop_ok < 0) {
        int nb = 0;
        hipError_t oe = hipOccupancyMaxActiveBlocksPerMultiprocessor(
            &nb, (const void*)k_mega, P1T, 0);
        coop_ok = (oe == hipSuccess && nb * 256 >= NB) ? 1 : 0;
    }

    hipError_t err = hipErrorUnknown;
    if (coop_ok) {
        void* args[] = { (void*)&train, (void*)&query, (void*)&labels,
                         (void*)&partial, (void*)&cand, (void*)&out };
        err = hipLaunchCooperativeKernel((const void*)k_mega, dim3(NB), dim3(P1T),
                                         args, 0, stream);
    }
    if (err != hipSuccess) {
        // fallback: identical phases as ordinary kernels (correct regardless of coop support)
        k_scale_f<<<NB, P1T, 0, stream>>>(train, partial);
        k_p1_f<<<NB, P1T, 0, stream>>>(train, query, partial, cand);
        k_p2_f<<<NB, P1T, 0, stream>>>(cand, train, query, labels, partial, out);
    }
}

// Round 11
// 216.280 us; speedup vs baseline: 2.4778x; 2.4778x over previous
//
#include <hip/hip_runtime.h>
#include <hip/hip_cooperative_groups.h>
#include <math.h>

namespace cg = cooperative_groups;

typedef _Float16 h8 __attribute__((ext_vector_type(8)));
typedef float    f4v __attribute__((ext_vector_type(4)));

#define N_TRAIN 400000
#define DIMS    27
#define BQ      512
#define NCLS    11
#define KNN     3
#define NB      500            // blocks: 2/CU x 256 CU = 512 co-resident slots >= 500
#define P1T     1024           // threads (16 waves)
#define PTS_BLK 800            // points per block (500*800 = 400000 exact)
#define PTS_SUP 80             // points per super-tile
#define NSUP    10             // super-tiles per block
#define NPT     5              // ptiles per super-tile (tiles/block = 50, fits 6 bits)
#define RAWF    2160           // floats per super-tile (80*27) = 8640 B
#define TILE_B  2048           // conv bytes per ptile: hi 1024 + lo 1024
#define CONVB   (NPT * TILE_B) // 10240 B (single buffer)
#define NC      (NB * KNN)     // candidates per query (1500)

#define U64MAX 0xFFFFFFFFFFFFFFFFULL

// lexicographic (key, idx) insert into ascending sorted triple — matches top_k ties
__device__ __forceinline__ void insert3(float d, int i, float* bd, int* bi) {
    if (d < bd[2] || (d == bd[2] && i < bi[2])) {
        if (d < bd[1] || (d == bd[1] && i < bi[1])) {
            bd[2] = bd[1]; bi[2] = bi[1];
            if (d < bd[0] || (d == bd[0] && i < bi[0])) {
                bd[1] = bd[0]; bi[1] = bi[0];
                bd[0] = d; bi[0] = i;
            } else { bd[1] = d; bi[1] = i; }
        } else { bd[2] = d; bi[2] = i; }
    }
}

// 64-bit xor-shuffle via two 32-bit shuffles
__device__ __forceinline__ unsigned long long shfl_xor_u64(unsigned long long v, int m) {
    unsigned lo = (unsigned)v, hi = (unsigned)(v >> 32);
    lo = __shfl_xor(lo, m, 64);
    hi = __shfl_xor(hi, m, 64);
    return ((unsigned long long)hi << 32) | lo;
}

// branchless insert into ascending sorted-3 of u64 (keep 3 smallest)
__device__ __forceinline__ void ins3u64(unsigned long long e,
                                        unsigned long long& t0,
                                        unsigned long long& t1,
                                        unsigned long long& t2) {
    unsigned long long a  = e < t2 ? e : t2;
    unsigned long long n2 = t1 > a ? t1 : a;
    unsigned long long n1 = t1 < a ? t1 : a;
    t2 = n2;
    unsigned long long m1 = t0 > n1 ? t0 : n1;
    t0 = t0 < n1 ? t0 : n1;
    t1 = m1;
}

// branchless compare-exchange (ascending)
#define CE(a, b) do { unsigned long long lo_ = (a) < (b) ? (a) : (b); \
                      unsigned long long hi_ = (a) < (b) ? (b) : (a); \
                      (a) = lo_; (b) = hi_; } while (0)

__device__ __forceinline__ void stage16(const float* g, float* l) {
    __builtin_amdgcn_global_load_lds((const __attribute__((address_space(1))) void*)g,
                                     (__attribute__((address_space(3))) void*)l, 16, 0, 0);
}

// =================== single template kernel: all phases MONOLITHIC ===================
// MODE 0 = fused cooperative (S -> grid.sync -> P1 -> grid.sync -> P2)
// MODE 1/2/3 = standalone S / P1 / P2 (non-cooperative fallback; R9-verified structure)
// LDS kept at ~22.6 KB so the occupancy model approves 2 blocks/CU (R9: 75.8KB -> rejected).
// Pipeline per super-tile (single raw + single convb):
//   barrier A (stage(s) drained, compute(s-1) done) -> conv(s) -> barrier B
//   -> stage(s+1) (flies through compute; drained at next barrier A) -> compute(s)
template<int MODE>
__global__ __attribute__((amdgpu_flat_work_group_size(P1T, P1T)))
__attribute__((amdgpu_waves_per_eu(4)))
void k_all(const float* __restrict__ train,
           const float* __restrict__ query,
           const float* __restrict__ labels,
           float* __restrict__ partial,
           unsigned long long* __restrict__ cand,
           float* __restrict__ out) {
    __shared__ float s_inv[32];
    __shared__ __align__(16) float raw[RAWF];                    // 8640 B (single buffer)
    __shared__ __align__(16) unsigned char convb[CONVB];         // 10240 B (single buffer)
    __shared__ float redS[4 * 32];                               // 512 B
    __shared__ float redP[16 * 32];                              // 2048 B
    __shared__ unsigned long long smerge[128];                   // 1024 B  (~22.6 KB total)

    int tid = threadIdx.x, bid = blockIdx.x;
    int lane = tid & 63, w = tid >> 6;
    int l15 = lane & 15, quad = lane >> 4;
    int p0 = bid * PTS_BLK;

    // ================= phase S: per-block max|row| over own 800 rows -> partial =================
    if (MODE == 0 || MODE == 1) {
        float m[DIMS];
#pragma unroll
        for (int d = 0; d < DIMS; ++d) m[d] = 0.f;
        if (tid < PTS_BLK / 4) {                   // 200 groups of 4 contiguous rows
            int g = bid * (PTS_BLK / 4) + tid;
            const uint4* p = (const uint4*)(train + (size_t)g * (4 * DIMS)); // 432B: 16B aligned
#pragma unroll
            for (int k = 0; k < DIMS; ++k) {       // column (4k+e)%27 is compile-time (rule #20)
                uint4 v = p[k];
                m[(4 * k + 0) % DIMS] = fmaxf(m[(4 * k + 0) % DIMS], fabsf(__uint_as_float(v.x)));
                m[(4 * k + 1) % DIMS] = fmaxf(m[(4 * k + 1) % DIMS], fabsf(__uint_as_float(v.y)));
                m[(4 * k + 2) % DIMS] = fmaxf(m[(4 * k + 2) % DIMS], fabsf(__uint_as_float(v.z)));
                m[(4 * k + 3) % DIMS] = fmaxf(m[(4 * k + 3) % DIMS], fabsf(__uint_as_float(v.w)));
            }
        }
        if (w < 4) {                               // only waves 0..3 hold rows (200 < 256)
#pragma unroll
            for (int d = 0; d < DIMS; ++d) {
                float t = m[d];
#pragma unroll
                for (int st = 1; st < 64; st <<= 1) t = fmaxf(t, __shfl_xor(t, st, 64));
                m[d] = t;
            }
            if (lane == 0) {
#pragma unroll
                for (int d = 0; d < DIMS; ++d) redS[w * 32 + d] = m[d];
            }
        }
        __syncthreads();
        if (tid < 32) {
            float v = 0.f;
            if (tid < DIMS) {
#pragma unroll
                for (int g2 = 0; g2 < 4; ++g2) v = fmaxf(v, redS[g2 * 32 + tid]);
            }
            partial[bid * 32 + tid] = v;           // dims 27..31 = 0 (fully written, no memset)
        }
    }
    if (MODE == 0) { __threadfence(); cg::this_grid().sync(); }

    // ================= phase P1: pipelined MFMA scan -> per-block top-3 per query =================
    if (MODE == 0 || MODE == 2) {
        const float* gsup = train + (size_t)p0 * DIMS;   // 16B aligned (800*108 % 16 == 0)

        // stage super-tile 0 (async; flies during scale reduce). 540 uint4s.
        if (tid < RAWF / 4) stage16(gsup + tid * 4, raw + tid * 4);

        // reduce NB x 32 partials -> s_inv (same values as the old atomicMax path)
        if (tid < 512) {
            int d = tid & 31, ch = tid >> 5;
            float v = 0.f;
            for (int b = ch; b < NB; b += 16) v = fmaxf(v, partial[b * 32 + d]);
            redP[ch * 32 + d] = v;
        }
        __syncthreads();                           // drains stage(0) vmcnt; redP ready
        if (tid < 32) {
            float sc = 0.f;
#pragma unroll
            for (int g2 = 0; g2 < 16; ++g2) sc = fmaxf(sc, redP[g2 * 32 + tid]);
            s_inv[tid] = (sc != 0.f) ? 1.f / sc : 0.f;  // divide_no_nan; 0 for d>=27
        }

        unsigned kb0[2][4], kb1[2][4];             // top-2 keys per (j,r); 0 = -inf sentinel
#pragma unroll
        for (int j = 0; j < 2; ++j)
#pragma unroll
            for (int r = 0; r < 4; ++r) { kb0[j][r] = 0u; kb1[j][r] = 0u; }
        const f4v z4 = {64.f, 64.f, 64.f, 64.f};   // +64 bias rides through MFMA C

        __syncthreads();                           // s_inv visible; raw[0] ready

        // conv(0): raw -> convb (320 tasks: point p, kblock gq)
        if (tid < PTS_SUP * 4) {
            int p = tid >> 2, gq = tid & 3;
            float x[8]; float part = 0.f;
#pragma unroll
            for (int i = 0; i < 8; ++i) {
                int d = gq * 8 + i;
                int dc = d < DIMS ? d : (DIMS - 1);
                float v = raw[p * DIMS + dc] * s_inv[d];
                x[i] = v;
                part = fmaf(v, v, part);
            }
            part += __shfl_xor(part, 1, 64);
            part += __shfl_xor(part, 2, 64);
            h8 hv, lv;
#pragma unroll
            for (int i = 0; i < 8; ++i) {
                _Float16 h = (_Float16)x[i];
                hv[i] = h;
                lv[i] = (_Float16)(x[i] - (float)h);
            }
            if (gq == 3) {
                float tt = -0.5f * part;
                _Float16 th = (_Float16)tt;
                hv[3] = th;
                lv[3] = (_Float16)(tt - (float)th);
            }
            unsigned char* dstb = convb + (p >> 4) * TILE_B + gq * 256 + (p & 15) * 16;
            *(h8*)dstb = hv;
            *(h8*)(dstb + 1024) = lv;
        }

        // in-register qprep (same op order as verified path); reads s_inv
        h8 bhi[2], blo[2];
#pragma unroll
        for (int j = 0; j < 2; ++j) {
            int q = (w * 2 + j) * 16 + l15;
            const float* qr = query + (size_t)q * DIMS;
#pragma unroll
            for (int i = 0; i < 8; ++i) {
                int d = quad * 8 + i;
                int dc = d < DIMS ? d : (DIMS - 1);
                float xs = qr[dc] * s_inv[d];
                _Float16 hi = (_Float16)xs;
                _Float16 lo = (_Float16)(xs - (float)hi);
                bool is27 = (d == 27);
                bhi[j][i] = is27 ? (_Float16)1.f : hi;
                blo[j][i] = is27 ? (_Float16)0.f : lo;
            }
        }

        // per-super-tile loop: {barrier B, stage(s+1), compute(s), barrier A, conv(s+1)}
        for (int s = 0; s < NSUP; ++s) {
            __syncthreads();                       // barrier B: conv(s) done -> convb ready
            if (s + 1 < NSUP) {                    // stage(s+1) into raw (conv(s) done reading)
                const float* gp = gsup + (size_t)(s + 1) * RAWF;
                if (tid < RAWF / 4) stage16(gp + tid * 4, raw + tid * 4);
            }
            // compute(s): 5 ptiles x 2 query-tiles x 3 MFMA + u32 top-2 update
            for (int t = 0; t < NPT; ++t) {
                const unsigned char* basep = convb + t * TILE_B;
                h8 ahi = *(const h8*)(basep + lane * 16);       // lane-linear: conflict-free
                h8 alo = *(const h8*)(basep + 1024 + lane * 16);
                unsigned ic = 63u - (unsigned)(s * NPT + t);    // wave-uniform tile code (6 bits)
#pragma unroll
                for (int j = 0; j < 2; ++j) {
                    f4v acc;
                    acc = __builtin_amdgcn_mfma_f32_16x16x32_f16(alo, bhi[j], z4, 0, 0, 0);
                    acc = __builtin_amdgcn_mfma_f32_16x16x32_f16(ahi, blo[j], acc, 0, 0, 0);
                    acc = __builtin_amdgcn_mfma_f32_16x16x32_f16(ahi, bhi[j], acc, 0, 0, 0);
#pragma unroll
                    for (int r = 0; r < 4; ++r) {
                        unsigned key = (__float_as_uint(acc[r]) & 0xFFFFFFC0u) | ic;  // and_or
                        unsigned b0 = kb0[j][r];
                        unsigned m  = key < b0 ? key : b0;      // v_min_u32
                        kb0[j][r]   = key > b0 ? key : b0;      // v_max_u32
                        unsigned b1 = kb1[j][r];
                        kb1[j][r]   = m > b1 ? m : b1;          // v_max_u32
                    }
                }
            }
            if (s + 1 < NSUP) {
                __syncthreads();                   // barrier A: stage(s+1) drained; compute(s) done
                // conv(s+1): raw -> convb (convb free: compute(s) done)
                if (tid < PTS_SUP * 4) {
                    int p = tid >> 2, gq = tid & 3;
                    float x[8]; float part = 0.f;
#pragma unroll
                    for (int i = 0; i < 8; ++i) {
                        int d = gq * 8 + i;
                        int dc = d < DIMS ? d : (DIMS - 1);
                        float v = raw[p * DIMS + dc] * s_inv[d];
                        x[i] = v;
                        part = fmaf(v, v, part);
                    }
                    part += __shfl_xor(part, 1, 64);
                    part += __shfl_xor(part, 2, 64);
                    h8 hv, lv;
#pragma unroll
                    for (int i = 0; i < 8; ++i) {
                        _Float16 h = (_Float16)x[i];
                        hv[i] = h;
                        lv[i] = (_Float16)(x[i] - (float)h);
                    }
                    if (gq == 3) {
                        float tt = -0.5f * part;
                        _Float16 th = (_Float16)tt;
                        hv[3] = th;
                        lv[3] = (_Float16)(tt - (float)th);
                    }
                    unsigned char* dstb = convb + (p >> 4) * TILE_B + gq * 256 + (p & 15) * 16;
                    *(h8*)dstb = hv;
                    *(h8*)(dstb + 1024) = lv;
                }
            }
        }

        // decode + cross-quad merge -> block top-3 per query -> cand
        int qr4 = quad * 4;
#pragma unroll
        for (int j = 0; j < 2; ++j) {
            unsigned long long t0 = U64MAX, t1 = U64MAX, t2 = U64MAX;
#pragma unroll
            for (int r = 0; r < 4; ++r) {
#pragma unroll
                for (int h = 0; h < 2; ++h) {
                    unsigned k = h ? kb1[j][r] : kb0[j][r];
                    unsigned tile = 63u - (k & 63u);
                    unsigned gi = (unsigned)(p0 + (int)tile * 16 + qr4 + r);
                    unsigned long long e = ((unsigned long long)(~(k | 63u)) << 32) | gi;
                    ins3u64(e, t0, t1, t2);
                }
            }
#pragma unroll
            for (int step = 16; step <= 32; step <<= 1) {
                unsigned long long o0 = shfl_xor_u64(t0, step);
                unsigned long long o1 = shfl_xor_u64(t1, step);
                unsigned long long o2 = shfl_xor_u64(t2, step);
                ins3u64(o0, t0, t1, t2);
                ins3u64(o1, t0, t1, t2);
                ins3u64(o2, t0, t1, t2);
            }
            if (quad == 0) {
                int qq = (w * 2 + j) * 16 + l15;
                size_t off = (size_t)qq * NC + (size_t)bid * KNN;
                cand[off + 0] = t0; cand[off + 1] = t1; cand[off + 2] = t2;
            }
        }
    }
    if (MODE == 0) { __threadfence(); cg::this_grid().sync(); }

    // standalone P2 must recompute s_inv from partial
    if (MODE == 3) {
        if (tid < 512) {
            int d = tid & 31, ch = tid >> 5;
            float v = 0.f;
            for (int b = ch; b < NB; b += 16) v = fmaxf(v, partial[b * 32 + d]);
            redP[ch * 32 + d] = v;
        }
        __syncthreads();
        if (tid < 32) {
            float sc = 0.f;
#pragma unroll
            for (int g2 = 0; g2 < 16; ++g2) sc = fmaxf(sc, redP[g2 * 32 + tid]);
            s_inv[tid] = (sc != 0.f) ? 1.f / sc : 0.f;
        }
        __syncthreads();
    }

    // ================= phase P2: u64 top-8 merge -> exact f32 refine -> vote =================
    if (MODE == 0 || MODE == 3) {
        for (int q = bid; q < BQ; q += NB) {       // blocks 0..11 handle two queries
            const unsigned long long* cd = cand + (size_t)q * NC;
            unsigned long long c0 = cd[tid];                                    // tid < 1500
            unsigned long long c1 = (tid + P1T < NC) ? cd[tid + P1T] : U64MAX;  // 476 threads
            CE(c0, c1);
#pragma unroll
            for (int k = 0; k < 8; ++k) {          // per-wave top-8 by butterfly-min extraction
                unsigned long long m = c0;
#pragma unroll
                for (int st = 1; st < 64; st <<= 1) {
                    unsigned long long o = shfl_xor_u64(m, st);
                    if (o < m) m = o;
                }
                if (lane == 0) smerge[w * 8 + k] = m;
                bool win = (c0 == m);
                c0 = win ? c1 : c0;
                c1 = win ? U64MAX : c1;
            }
            __syncthreads();

            if (w == 0) {
                // merge 128 wave winners -> global top-8; lane k keeps idx of rank k
                int myi = 0x7fffffff;
                unsigned long long e0 = smerge[lane], e1 = smerge[64 + lane];
                CE(e0, e1);
#pragma unroll
                for (int k = 0; k < 8; ++k) {
                    unsigned long long m = e0;
#pragma unroll
                    for (int st = 1; st < 64; st <<= 1) {
                        unsigned long long o = shfl_xor_u64(m, st);
                        if (o < m) m = o;
                    }
                    if (lane == k) myi = (int)(unsigned)m;
                    bool win = (e0 == m);
                    e0 = win ? e1 : e0;
                    e1 = win ? U64MAX : e1;
                }

                // exact refine — same op order as the verified path
                float qn_ = 0.f;
#pragma unroll
                for (int d = 0; d < DIMS; ++d) {
                    float v = query[(size_t)q * DIMS + d] * s_inv[d];
                    qn_ = fmaf(v, v, qn_);
                }
                float myd2 = 3.4e38f;
                if (lane < 8) {
                    const float* r = train + (size_t)myi * DIMS;
                    float xnv = 0.f, dot = 0.f;
#pragma unroll
                    for (int d = 0; d < DIMS; ++d) {
                        float iv = s_inv[d];
                        float qv = query[(size_t)q * DIMS + d] * iv;
                        float tv = r[d] * iv;
                        xnv = fmaf(tv, tv, xnv);
                        dot = fmaf(qv, tv, dot);
                    }
                    myd2 = fmaf(-2.f, dot, qn_ + xnv);
                }

                float bd[KNN] = {3.4e38f, 3.4e38f, 3.4e38f};
                int   bi[KNN] = {0x7fffffff, 0x7fffffff, 0x7fffffff};
#pragma unroll
                for (int k = 0; k < 8; ++k) {
                    float dk = __shfl(myd2, k, 64);
                    int   ik = __shfl(myi, k, 64);
                    insert3(dk, ik, bd, bi);
                }

                if (lane == 0) {
                    float kd[KNN];
#pragma unroll
                    for (int k = 0; k < KNN; ++k) kd[k] = sqrtf(fmaxf(bd[k], 0.f));
                    float votes[NCLS];
#pragma unroll
                    for (int c = 0; c < NCLS; ++c) votes[c] = 0.f;
#pragma unroll
                    for (int k = 0; k < KNN; ++k) {
                        float ks = (kd[k] == 0.f) ? 1.f : kd[k];
                        const float* lr = labels + (size_t)bi[k] * NCLS;
#pragma unroll
                        for (int c = 0; c < NCLS; ++c) votes[c] += lr[c] / ks;
                    }
                    int best = 0; float bv = votes[0];
#pragma unroll
                    for (int c = 1; c < NCLS; ++c) { if (votes[c] > bv) { bv = votes[c]; best = c; } }
                    bool zero_hit = (kd[0] == 0.f);
#pragma unroll
                    for (int k = 0; k < KNN; ++k) out[(size_t)q * KNN + k] = kd[k];
                    const float* l0 = labels + (size_t)bi[0] * NCLS;
                    float* ro = out + (size_t)BQ * KNN + (size_t)q * NCLS;
#pragma unroll
                    for (int c = 0; c < NCLS; ++c)
                        ro[c] = zero_hit ? l0[c] : ((c == best) ? 1.f : 0.f);
                }
            }
            __syncthreads();                       // smerge reuse guard between q iterations
        }
    }
}

extern "C" void kernel_launch(void* const* d_in, const int* in_sizes, int n_in,
                              void* d_out, int out_size, void* d_ws, size_t ws_size,
                              hipStream_t stream) {
    const float* query  = (const float*)d_in[0];
    const float* train  = (const float*)d_in[1];
    const float* labels = (const float*)d_in[2];
    float* out = (float*)d_out;

    // ws layout:
    //   [0)      partial: 500*32 f32 (64000 B, fully written -> no memset)
    //   [65536)  cand: 512*1500 u64 (6144000 B)
    char* ws = (char*)d_ws;
    float* partial = (float*)ws;
    unsigned long long* cand = (unsigned long long*)(ws + 65536);

    // pre-gate (host-side, capture-safe): only attempt cooperative launch if the runtime's
    // own occupancy model promises 2 blocks/CU (500 blocks co-resident on 256 CUs).
    static int coop_ok = -1;
    if (coop_ok < 0) {
        int nb = 0;
        hipError_t oe = hipOccupancyMaxActiveBlocksPerMultiprocessor(
            &nb, (const void*)(&k_all<0>), P1T, 0);
        coop_ok = (oe == hipSuccess && nb >= 2) ? 1 : 0;
    }

    hipError_t err = hipErrorUnknown;
    if (coop_ok) {
        void* args[] = { (void*)&train, (void*)&query, (void*)&labels,
                         (void*)&partial, (void*)&cand, (void*)&out };
        err = hipLaunchCooperativeKernel((const void*)(&k_all<0>), dim3(NB), dim3(P1T),
                                         args, 0, stream);
    }
    if (err != hipSuccess) {
        // fallback: identical monolithic phases as ordinary kernels (R9-verified structure)
        k_all<1><<<NB, P1T, 0, stream>>>(train, query, labels, partial, cand, out);
        k_all<2><<<NB, P1T, 0, stream>>>(train, query, labels, partial, cand, out);
        k_all<3><<<NB, P1T, 0, stream>>>(train, query, labels, partial, cand, out);
    }
}

// Round 12
// 190.730 us; speedup vs baseline: 2.8097x; 1.1340x over previous
//
#include <hip/hip_runtime.h>
#include <hip/hip_cooperative_groups.h>
#include <math.h>

namespace cg = cooperative_groups;

typedef _Float16 h8 __attribute__((ext_vector_type(8)));
typedef float    f4v __attribute__((ext_vector_type(4)));

#define N_TRAIN 400000
#define DIMS    27
#define BQ      512
#define NCLS    11
#define KNN     3
#define NB      250            // blocks: coop runtime caps at 1 blk/CU; 250 <= 256 CUs (R8-proven)
#define P1T     1024           // threads (16 waves)
#define PTS_BLK 1600           // points per block (250*1600 = 400000 exact)
#define PTS_SUP 160            // points per super-tile
#define NSUP    10             // super-tiles per block (tiles/block = 100, fits 7 bits)
#define NPT     10             // ptiles per super-tile
#define RAWF    4320           // floats per super-tile (160*27) = 17280 B
#define TILE_B  2048           // conv bytes per ptile: hi 1024 + lo 1024
#define CONVB   (NPT * TILE_B) // 20480 B per conv buffer
#define NC      (NB * KNN)     // candidates per query (750)

#define U64MAX 0xFFFFFFFFFFFFFFFFULL

// lexicographic (key, idx) insert into ascending sorted triple — matches top_k ties
__device__ __forceinline__ void insert3(float d, int i, float* bd, int* bi) {
    if (d < bd[2] || (d == bd[2] && i < bi[2])) {
        if (d < bd[1] || (d == bd[1] && i < bi[1])) {
            bd[2] = bd[1]; bi[2] = bi[1];
            if (d < bd[0] || (d == bd[0] && i < bi[0])) {
                bd[1] = bd[0]; bi[1] = bi[0];
                bd[0] = d; bi[0] = i;
            } else { bd[1] = d; bi[1] = i; }
        } else { bd[2] = d; bi[2] = i; }
    }
}

// 64-bit xor-shuffle via two 32-bit shuffles
__device__ __forceinline__ unsigned long long shfl_xor_u64(unsigned long long v, int m) {
    unsigned lo = (unsigned)v, hi = (unsigned)(v >> 32);
    lo = __shfl_xor(lo, m, 64);
    hi = __shfl_xor(hi, m, 64);
    return ((unsigned long long)hi << 32) | lo;
}

// branchless insert into ascending sorted-3 of u64 (keep 3 smallest)
__device__ __forceinline__ void ins3u64(unsigned long long e,
                                        unsigned long long& t0,
                                        unsigned long long& t1,
                                        unsigned long long& t2) {
    unsigned long long a  = e < t2 ? e : t2;
    unsigned long long n2 = t1 > a ? t1 : a;
    unsigned long long n1 = t1 < a ? t1 : a;
    t2 = n2;
    unsigned long long m1 = t0 > n1 ? t0 : n1;
    t0 = t0 < n1 ? t0 : n1;
    t1 = m1;
}

// branchless compare-exchange (ascending)
#define CE(a, b) do { unsigned long long lo_ = (a) < (b) ? (a) : (b); \
                      unsigned long long hi_ = (a) < (b) ? (b) : (a); \
                      (a) = lo_; (b) = hi_; } while (0)

__device__ __forceinline__ void stage16(const float* g, float* l) {
    __builtin_amdgcn_global_load_lds((const __attribute__((address_space(1))) void*)g,
                                     (__attribute__((address_space(3))) void*)l, 16, 0, 0);
}

// =================== single template kernel: all phases MONOLITHIC ===================
// MODE 0 = fused cooperative (S -> grid.sync -> P1 -> grid.sync -> P2)
// MODE 1/2/3 = standalone S / P1 / P2 (non-cooperative fallback)
// Lessons encoded here: (R9) NO pointer-passed __shared__ helpers (4.4x poison) — all bodies
// inline on directly-declared __shared__ arrays; (R8) coop launch accepted at NB=250 with
// ~76KB LDS; (R5) one-barrier double-buffered pipeline is the fast P1 schedule.
template<int MODE>
__global__ __attribute__((amdgpu_flat_work_group_size(P1T, P1T)))
__attribute__((amdgpu_waves_per_eu(4)))
void k_all(const float* __restrict__ train,
           const float* __restrict__ query,
           const float* __restrict__ labels,
           float* __restrict__ partial,
           unsigned long long* __restrict__ cand,
           float* __restrict__ out) {
    __shared__ float s_inv[32];
    __shared__ __align__(16) float raw[2][RAWF];                 // 34560 B (double buffer)
    __shared__ __align__(16) unsigned char convb[2][CONVB];      // 40960 B (double buffer)
    __shared__ float redS[7 * 32];                               // 896 B
    __shared__ float redP[16 * 32];                              // 2048 B
    __shared__ unsigned long long smerge[128];                   // 1024 B  (~79.6 KB total)

    int tid = threadIdx.x, bid = blockIdx.x;
    int lane = tid & 63, w = tid >> 6;
    int l15 = lane & 15, quad = lane >> 4;
    int p0 = bid * PTS_BLK;

    // ================= phase S: per-block max|row| over own 1600 rows -> partial =================
    if (MODE == 0 || MODE == 1) {
        float m[DIMS];
#pragma unroll
        for (int d = 0; d < DIMS; ++d) m[d] = 0.f;
        if (tid < PTS_BLK / 4) {                   // 400 groups of 4 contiguous rows
            int g = bid * (PTS_BLK / 4) + tid;
            const uint4* p = (const uint4*)(train + (size_t)g * (4 * DIMS)); // 432B: 16B aligned
#pragma unroll
            for (int k = 0; k < DIMS; ++k) {       // column (4k+e)%27 is compile-time (rule #20)
                uint4 v = p[k];
                m[(4 * k + 0) % DIMS] = fmaxf(m[(4 * k + 0) % DIMS], fabsf(__uint_as_float(v.x)));
                m[(4 * k + 1) % DIMS] = fmaxf(m[(4 * k + 1) % DIMS], fabsf(__uint_as_float(v.y)));
                m[(4 * k + 2) % DIMS] = fmaxf(m[(4 * k + 2) % DIMS], fabsf(__uint_as_float(v.z)));
                m[(4 * k + 3) % DIMS] = fmaxf(m[(4 * k + 3) % DIMS], fabsf(__uint_as_float(v.w)));
            }
        }
        if (w < 7) {                               // waves 0..6 hold rows (400 = 6*64 + 16)
#pragma unroll
            for (int d = 0; d < DIMS; ++d) {
                float t = m[d];
#pragma unroll
                for (int st = 1; st < 64; st <<= 1) t = fmaxf(t, __shfl_xor(t, st, 64));
                m[d] = t;
            }
            if (lane == 0) {
#pragma unroll
                for (int d = 0; d < DIMS; ++d) redS[w * 32 + d] = m[d];
            }
        }
        __syncthreads();
        if (tid < 32) {
            float v = 0.f;
            if (tid < DIMS) {
#pragma unroll
                for (int g2 = 0; g2 < 7; ++g2) v = fmaxf(v, redS[g2 * 32 + tid]);
            }
            partial[bid * 32 + tid] = v;           // dims 27..31 = 0 (fully written, no memset)
        }
    }
    if (MODE == 0) { __threadfence(); cg::this_grid().sync(); }

    // ================= phase P1: pipelined MFMA scan -> per-block top-3 per query =================
    if (MODE == 0 || MODE == 2) {
        const float* gsup = train + (size_t)p0 * DIMS;   // 16B aligned (1600*108 % 16 == 0)

        // stage super-tile 0 (async; flies during scale reduce): 4096 + 224 floats
        stage16(gsup + tid * 4, &raw[0][0] + tid * 4);
        if (tid < 56) stage16(gsup + 4096 + tid * 4, &raw[0][0] + 4096 + tid * 4);

        // reduce NB x 32 partials -> s_inv (same values as the old atomicMax path)
        if (tid < 512) {
            int d = tid & 31, ch = tid >> 5;
            float v = 0.f;
            for (int b = ch; b < NB; b += 16) v = fmaxf(v, partial[b * 32 + d]);
            redP[ch * 32 + d] = v;
        }
        __syncthreads();                           // drains stage(0) vmcnt; redP ready
        if (tid < 32) {
            float sc = 0.f;
#pragma unroll
            for (int g2 = 0; g2 < 16; ++g2) sc = fmaxf(sc, redP[g2 * 32 + tid]);
            s_inv[tid] = (sc != 0.f) ? 1.f / sc : 0.f;  // divide_no_nan; 0 for d>=27
        }

        unsigned kb0[2][4], kb1[2][4];             // top-2 keys per (j,r); 0 = -inf sentinel
#pragma unroll
        for (int j = 0; j < 2; ++j)
#pragma unroll
            for (int r = 0; r < 4; ++r) { kb0[j][r] = 0u; kb1[j][r] = 0u; }
        const f4v z4 = {64.f, 64.f, 64.f, 64.f};   // +64 bias rides through MFMA C

        __syncthreads();                           // barrier A: s_inv visible; raw[0] ready

        // stage super-tile 1 -> raw[1] (drains at first loop barrier)
        stage16(gsup + RAWF + tid * 4, &raw[1][0] + tid * 4);
        if (tid < 56) stage16(gsup + RAWF + 4096 + tid * 4, &raw[1][0] + 4096 + tid * 4);

        // conv(0): raw[0] -> convb[0] (640 tasks: point p, kblock gq; waves 0..9)
        if (tid < PTS_SUP * 4) {
            int p = tid >> 2, gq = tid & 3;
            float x[8]; float part = 0.f;
#pragma unroll
            for (int i = 0; i < 8; ++i) {
                int d = gq * 8 + i;
                int dc = d < DIMS ? d : (DIMS - 1);
                float v = raw[0][p * DIMS + dc] * s_inv[d];
                x[i] = v;
                part = fmaf(v, v, part);
            }
            part += __shfl_xor(part, 1, 64);
            part += __shfl_xor(part, 2, 64);
            h8 hv, lv;
#pragma unroll
            for (int i = 0; i < 8; ++i) {
                _Float16 h = (_Float16)x[i];
                hv[i] = h;
                lv[i] = (_Float16)(x[i] - (float)h);
            }
            if (gq == 3) {
                float tt = -0.5f * part;
                _Float16 th = (_Float16)tt;
                hv[3] = th;
                lv[3] = (_Float16)(tt - (float)th);
            }
            unsigned char* dstb = &convb[0][0] + (p >> 4) * TILE_B + gq * 256 + (p & 15) * 16;
            *(h8*)dstb = hv;
            *(h8*)(dstb + 1024) = lv;
        }

        // in-register qprep (same op order as verified path); reads s_inv
        h8 bhi[2], blo[2];
#pragma unroll
        for (int j = 0; j < 2; ++j) {
            int q = (w * 2 + j) * 16 + l15;
            const float* qr = query + (size_t)q * DIMS;
#pragma unroll
            for (int i = 0; i < 8; ++i) {
                int d = quad * 8 + i;
                int dc = d < DIMS ? d : (DIMS - 1);
                float xs = qr[dc] * s_inv[d];
                _Float16 hi = (_Float16)xs;
                _Float16 lo = (_Float16)(xs - (float)hi);
                bool is27 = (d == 27);
                bhi[j][i] = is27 ? (_Float16)1.f : hi;
                blo[j][i] = is27 ? (_Float16)0.f : lo;
            }
        }

        // pipeline: barrier, stage(s+1), conv(s), compute(s-1)   [one barrier per super-tile]
        for (int s = 1; s < NSUP; ++s) {
            __syncthreads();   // drains stage(s) -> raw[s&1] ready; convb[s&1] free (compute(s-2) done)
            if (s + 1 < NSUP) {
                const float* gp = gsup + (size_t)(s + 1) * RAWF;
                float* lp = &raw[(s + 1) & 1][0];
                stage16(gp + tid * 4, lp + tid * 4);
                if (tid < 56) stage16(gp + 4096 + tid * 4, lp + 4096 + tid * 4);
            }
            {   // conv(s): raw[s&1] -> convb[s&1]
                const float* rw = &raw[s & 1][0];
                unsigned char* cv = &convb[s & 1][0];
                if (tid < PTS_SUP * 4) {
                    int p = tid >> 2, gq = tid & 3;
                    float x[8]; float part = 0.f;
#pragma unroll
                    for (int i = 0; i < 8; ++i) {
                        int d = gq * 8 + i;
                        int dc = d < DIMS ? d : (DIMS - 1);
                        float v = rw[p * DIMS + dc] * s_inv[d];
                        x[i] = v;
                        part = fmaf(v, v, part);
                    }
                    part += __shfl_xor(part, 1, 64);
                    part += __shfl_xor(part, 2, 64);
                    h8 hv, lv;
#pragma unroll
                    for (int i = 0; i < 8; ++i) {
                        _Float16 h = (_Float16)x[i];
                        hv[i] = h;
                        lv[i] = (_Float16)(x[i] - (float)h);
                    }
                    if (gq == 3) {
                        float tt = -0.5f * part;
                        _Float16 th = (_Float16)tt;
                        hv[3] = th;
                        lv[3] = (_Float16)(tt - (float)th);
                    }
                    unsigned char* dstb = cv + (p >> 4) * TILE_B + gq * 256 + (p & 15) * 16;
                    *(h8*)dstb = hv;
                    *(h8*)(dstb + 1024) = lv;
                }
            }
            {   // compute(s-1): 10 ptiles x 2 query-tiles x 3 MFMA + u32 top-2 update (7-bit tile)
                int ss = s - 1;
                const unsigned char* cb = &convb[ss & 1][0];
                for (int t = 0; t < NPT; ++t) {
                    const unsigned char* basep = cb + t * TILE_B;
                    h8 ahi = *(const h8*)(basep + lane * 16);   // lane-linear: conflict-free
                    h8 alo = *(const h8*)(basep + 1024 + lane * 16);
                    unsigned ic = 127u - (unsigned)(ss * NPT + t);
#pragma unroll
                    for (int j = 0; j < 2; ++j) {
                        f4v acc;
                        acc = __builtin_amdgcn_mfma_f32_16x16x32_f16(alo, bhi[j], z4, 0, 0, 0);
                        acc = __builtin_amdgcn_mfma_f32_16x16x32_f16(ahi, blo[j], acc, 0, 0, 0);
                        acc = __builtin_amdgcn_mfma_f32_16x16x32_f16(ahi, bhi[j], acc, 0, 0, 0);
#pragma unroll
                        for (int r = 0; r < 4; ++r) {
                            unsigned key = (__float_as_uint(acc[r]) & 0xFFFFFF80u) | ic;
                            unsigned b0 = kb0[j][r];
                            unsigned m  = key < b0 ? key : b0;
                            kb0[j][r]   = key > b0 ? key : b0;
                            unsigned b1 = kb1[j][r];
                            kb1[j][r]   = m > b1 ? m : b1;
                        }
                    }
                }
            }
        }
        __syncthreads();
        {   // epilogue: compute(NSUP-1)
            int ss = NSUP - 1;
            const unsigned char* cb = &convb[ss & 1][0];
            for (int t = 0; t < NPT; ++t) {
                const unsigned char* basep = cb + t * TILE_B;
                h8 ahi = *(const h8*)(basep + lane * 16);
                h8 alo = *(const h8*)(basep + 1024 + lane * 16);
                unsigned ic = 127u - (unsigned)(ss * NPT + t);
#pragma unroll
                for (int j = 0; j < 2; ++j) {
                    f4v acc;
                    acc = __builtin_amdgcn_mfma_f32_16x16x32_f16(alo, bhi[j], z4, 0, 0, 0);
                    acc = __builtin_amdgcn_mfma_f32_16x16x32_f16(ahi, blo[j], acc, 0, 0, 0);
                    acc = __builtin_amdgcn_mfma_f32_16x16x32_f16(ahi, bhi[j], acc, 0, 0, 0);
#pragma unroll
                    for (int r = 0; r < 4; ++r) {
                        unsigned key = (__float_as_uint(acc[r]) & 0xFFFFFF80u) | ic;
                        unsigned b0 = kb0[j][r];
                        unsigned m  = key < b0 ? key : b0;
                        kb0[j][r]   = key > b0 ? key : b0;
                        unsigned b1 = kb1[j][r];
                        kb1[j][r]   = m > b1 ? m : b1;
                    }
                }
            }
        }

        // decode + cross-quad merge -> block top-3 per query -> cand
        int qr4 = quad * 4;
#pragma unroll
        for (int j = 0; j < 2; ++j) {
            unsigned long long t0 = U64MAX, t1 = U64MAX, t2 = U64MAX;
#pragma unroll
            for (int r = 0; r < 4; ++r) {
#pragma unroll
                for (int h = 0; h < 2; ++h) {
                    unsigned k = h ? kb1[j][r] : kb0[j][r];
                    unsigned tile = 127u - (k & 127u);
                    unsigned gi = (unsigned)(p0 + (int)tile * 16 + qr4 + r);
                    unsigned long long e = ((unsigned long long)(~(k | 127u)) << 32) | gi;
                    ins3u64(e, t0, t1, t2);
                }
            }
#pragma unroll
            for (int step = 16; step <= 32; step <<= 1) {
                unsigned long long o0 = shfl_xor_u64(t0, step);
                unsigned long long o1 = shfl_xor_u64(t1, step);
                unsigned long long o2 = shfl_xor_u64(t2, step);
                ins3u64(o0, t0, t1, t2);
                ins3u64(o1, t0, t1, t2);
                ins3u64(o2, t0, t1, t2);
            }
            if (quad == 0) {
                int qq = (w * 2 + j) * 16 + l15;
                size_t off = (size_t)qq * NC + (size_t)bid * KNN;
                cand[off + 0] = t0; cand[off + 1] = t1; cand[off + 2] = t2;
            }
        }
    }
    if (MODE == 0) { __threadfence(); cg::this_grid().sync(); }

    // standalone P2 must recompute s_inv from partial
    if (MODE == 3) {
        if (tid < 512) {
            int d = tid & 31, ch = tid >> 5;
            float v = 0.f;
            for (int b = ch; b < NB; b += 16) v = fmaxf(v, partial[b * 32 + d]);
            redP[ch * 32 + d] = v;
        }
        __syncthreads();
        if (tid < 32) {
            float sc = 0.f;
#pragma unroll
            for (int g2 = 0; g2 < 16; ++g2) sc = fmaxf(sc, redP[g2 * 32 + tid]);
            s_inv[tid] = (sc != 0.f) ? 1.f / sc : 0.f;
        }
        __syncthreads();
    }

    // ================= phase P2: u64 top-8 merge -> exact f32 refine -> vote =================
    if (MODE == 0 || MODE == 3) {
        for (int q = bid; q < BQ; q += NB) {       // blocks 0..11 handle 3 queries, rest 2
            const unsigned long long* cd = cand + (size_t)q * NC;
            unsigned long long c0 = (tid < NC) ? cd[tid] : U64MAX;  // 1 candidate/thread (750)
#pragma unroll
            for (int k = 0; k < 8; ++k) {          // per-wave top-8 by butterfly-min extraction
                unsigned long long m = c0;
#pragma unroll
                for (int st = 1; st < 64; st <<= 1) {
                    unsigned long long o = shfl_xor_u64(m, st);
                    if (o < m) m = o;
                }
                if (lane == 0) smerge[w * 8 + k] = m;
                c0 = (c0 == m) ? U64MAX : c0;      // unique pop (distinct idx); all-MAX waves benign
            }
            __syncthreads();

            if (w == 0) {
                // merge 128 wave winners -> global top-8; lane k keeps idx of rank k
                int myi = 0x7fffffff;
                unsigned long long e0 = smerge[lane], e1 = smerge[64 + lane];
                CE(e0, e1);
#pragma unroll
                for (int k = 0; k < 8; ++k) {
                    unsigned long long m = e0;
#pragma unroll
                    for (int st = 1; st < 64; st <<= 1) {
                        unsigned long long o = shfl_xor_u64(m, st);
                        if (o < m) m = o;
                    }
                    if (lane == k) myi = (int)(unsigned)m;
                    bool win = (e0 == m);
                    e0 = win ? e1 : e0;
                    e1 = win ? U64MAX : e1;
                }

                // exact refine — same op order as the verified path
                float qn_ = 0.f;
#pragma unroll
                for (int d = 0; d < DIMS; ++d) {
                    float v = query[(size_t)q * DIMS + d] * s_inv[d];
                    qn_ = fmaf(v, v, qn_);
                }
                float myd2 = 3.4e38f;
                if (lane < 8) {
                    const float* r = train + (size_t)myi * DIMS;
                    float xnv = 0.f, dot = 0.f;
#pragma unroll
                    for (int d = 0; d < DIMS; ++d) {
                        float iv = s_inv[d];
                        float qv = query[(size_t)q * DIMS + d] * iv;
                        float tv = r[d] * iv;
                        xnv = fmaf(tv, tv, xnv);
                        dot = fmaf(qv, tv, dot);
                    }
                    myd2 = fmaf(-2.f, dot, qn_ + xnv);
                }

                float bd[KNN] = {3.4e38f, 3.4e38f, 3.4e38f};
                int   bi[KNN] = {0x7fffffff, 0x7fffffff, 0x7fffffff};
#pragma unroll
                for (int k = 0; k < 8; ++k) {
                    float dk = __shfl(myd2, k, 64);
                    int   ik = __shfl(myi, k, 64);
                    insert3(dk, ik, bd, bi);
                }

                if (lane == 0) {
                    float kd[KNN];
#pragma unroll
                    for (int k = 0; k < KNN; ++k) kd[k] = sqrtf(fmaxf(bd[k], 0.f));
                    float votes[NCLS];
#pragma unroll
                    for (int c = 0; c < NCLS; ++c) votes[c] = 0.f;
#pragma unroll
                    for (int k = 0; k < KNN; ++k) {
                        float ks = (kd[k] == 0.f) ? 1.f : kd[k];
                        const float* lr = labels + (size_t)bi[k] * NCLS;
#pragma unroll
                        for (int c = 0; c < NCLS; ++c) votes[c] += lr[c] / ks;
                    }
                    int best = 0; float bv = votes[0];
#pragma unroll
                    for (int c = 1; c < NCLS; ++c) { if (votes[c] > bv) { bv = votes[c]; best = c; } }
                    bool zero_hit = (kd[0] == 0.f);
#pragma unroll
                    for (int k = 0; k < KNN; ++k) out[(size_t)q * KNN + k] = kd[k];
                    const float* l0 = labels + (size_t)bi[0] * NCLS;
                    float* ro = out + (size_t)BQ * KNN + (size_t)q * NCLS;
#pragma unroll
                    for (int c = 0; c < NCLS; ++c)
                        ro[c] = zero_hit ? l0[c] : ((c == best) ? 1.f : 0.f);
                }
            }
            __syncthreads();                       // smerge reuse guard between q iterations
        }
    }
}

extern "C" void kernel_launch(void* const* d_in, const int* in_sizes, int n_in,
                              void* d_out, int out_size, void* d_ws, size_t ws_size,
                              hipStream_t stream) {
    const float* query  = (const float*)d_in[0];
    const float* train  = (const float*)d_in[1];
    const float* labels = (const float*)d_in[2];
    float* out = (float*)d_out;

    // ws layout:
    //   [0)      partial: 250*32 f32 (32000 B, fully written -> no memset)
    //   [32768)  cand: 512*750 u64 (3072000 B)
    char* ws = (char*)d_ws;
    float* partial = (float*)ws;
    unsigned long long* cand = (unsigned long long*)(ws + 32768);

    // pre-gate (host-side, capture-safe): NB=250 needs only 1 block/CU (R8-proven accepted)
    static int coop_ok = -1;
    if (coop_ok < 0) {
        int nb = 0;
        hipError_t oe = hipOccupancyMaxActiveBlocksPerMultiprocessor(
            &nb, (const void*)(&k_all<0>), P1T, 0);
        coop_ok = (oe == hipSuccess && nb >= 1) ? 1 : 0;
    }

    hipError_t err = hipErrorUnknown;
    if (coop_ok) {
        void* args[] = { (void*)&train, (void*)&query, (void*)&labels,
                         (void*)&partial, (void*)&cand, (void*)&out };
        err = hipLaunchCooperativeKernel((const void*)(&k_all<0>), dim3(NB), dim3(P1T),
                                         args, 0, stream);
    }
    if (err != hipSuccess) {
        // fallback: identical monolithic phases as ordinary kernels (R11-verified structure)
        k_all<1><<<NB, P1T, 0, stream>>>(train, query, labels, partial, cand, out);
        k_all<2><<<NB, P1T, 0, stream>>>(train, query, labels, partial, cand, out);
        k_all<3><<<NB, P1T, 0, stream>>>(train, query, labels, partial, cand, out);
    }
}

// Round 13
// 170.838 us; speedup vs baseline: 3.1369x; 1.1164x over previous
//
#include <hip/hip_runtime.h>
#include <math.h>

typedef _Float16 h8 __attribute__((ext_vector_type(8)));
typedef float    f4v __attribute__((ext_vector_type(4)));

#define N_TRAIN 400000
#define DIMS    27
#define BQ      512
#define NCLS    11
#define KNN     3
#define NB      500            // pass-1 blocks
#define P1T     1024           // pass-1 threads (16 waves)
#define PTS_BLK 800            // points per block (500*800 = 400000 exact)
#define PTS_SUP 160            // points per super-tile
#define NSUP    5
#define NPT     10
#define RAWF    4320           // floats per super-tile (160*27)
#define TILE_B  2048           // conv bytes per ptile: hi 1024 + lo 1024
#define NC      (NB * KNN)     // candidates per query (1500)
#define SCB     391            // k_scale blocks (391*256 = 100096 >= 100000 groups of 4 rows)
#define P2T     512            // pass-2 threads (8 waves)

#define U64MAX 0xFFFFFFFFFFFFFFFFULL

// ---------------- scale = max(|train|, axis=0) — register-resident, no LDS staging ----------------
// (R6-verified kernel.) Each thread owns 4 CONTIGUOUS rows = 108 floats = 27 uint4 (16B aligned:
// g*432 % 16 == 0). Column of float e of uint4 k is (4k+e) % 27 — compile-time under full unroll,
// so the 27 per-thread maxes live in registers (rule #20). fmaxf(m, fabsf(x)) folds to v_max |x|.
__global__ __launch_bounds__(256) void k_scale(const float* __restrict__ train,
                                               unsigned* __restrict__ scale_u) {
    __shared__ float red[4][DIMS];
    int tid = threadIdx.x;
    int lane = tid & 63, w = tid >> 6;
    int g = blockIdx.x * 256 + tid;            // 4-row group id
    float m[DIMS];
#pragma unroll
    for (int d = 0; d < DIMS; ++d) m[d] = 0.f;
    if (g < N_TRAIN / 4) {
        const uint4* p = (const uint4*)(train + (size_t)g * (4 * DIMS));
#pragma unroll
        for (int k = 0; k < DIMS; ++k) {
            uint4 v = p[k];
            m[(4 * k + 0) % DIMS] = fmaxf(m[(4 * k + 0) % DIMS], fabsf(__uint_as_float(v.x)));
            m[(4 * k + 1) % DIMS] = fmaxf(m[(4 * k + 1) % DIMS], fabsf(__uint_as_float(v.y)));
            m[(4 * k + 2) % DIMS] = fmaxf(m[(4 * k + 2) % DIMS], fabsf(__uint_as_float(v.z)));
            m[(4 * k + 3) % DIMS] = fmaxf(m[(4 * k + 3) % DIMS], fabsf(__uint_as_float(v.w)));
        }
    }
    // wave butterfly reduce (27 dims x 6 steps)
#pragma unroll
    for (int d = 0; d < DIMS; ++d) {
        float t = m[d];
#pragma unroll
        for (int st = 1; st < 64; st <<= 1) t = fmaxf(t, __shfl_xor(t, st, 64));
        m[d] = t;
    }
    if (lane == 0) {
#pragma unroll
        for (int d = 0; d < DIMS; ++d) red[w][d] = m[d];
    }
    __syncthreads();
    if (tid < DIMS) {
        float v = fmaxf(fmaxf(red[0][tid], red[1][tid]), fmaxf(red[2][tid], red[3][tid]));
        atomicMax(&scale_u[tid], __float_as_uint(v)); // values >= 0: uint order == float order
    }
}

// ---------------- query prep: split-f16 B-fragments, k=27 slot = {1,0} ----------------
__global__ __launch_bounds__(64) void k_qprep(const float* __restrict__ query,
                                              const unsigned* __restrict__ scale_u,
                                              _Float16* __restrict__ Qhi,
                                              _Float16* __restrict__ Qlo) {
    int q = blockIdx.x * 64 + threadIdx.x;
    if (q >= BQ) return;
    const float* r = query + (size_t)q * DIMS;
#pragma unroll
    for (int d = 0; d < 32; ++d) {
        _Float16 hi = (_Float16)0.f, lo = (_Float16)0.f;
        if (d < DIMS) {
            float sc = __uint_as_float(scale_u[d]);
            float inv = (sc != 0.f) ? 1.f / sc : 0.f;   // divide_no_nan
            float xs = r[d] * inv;
            hi = (_Float16)xs;
            lo = (_Float16)(xs - (float)hi);
        } else if (d == 27) {
            hi = (_Float16)1.f;   // multiplies A's -xn/2 hi+lo slots
        }
        Qhi[q * 32 + d] = hi;
        Qlo[q * 32 + d] = lo;
    }
}

// lexicographic (key, idx) insert into ascending sorted triple — matches top_k ties
__device__ __forceinline__ void insert3(float d, int i, float* bd, int* bi) {
    if (d < bd[2] || (d == bd[2] && i < bi[2])) {
        if (d < bd[1] || (d == bd[1] && i < bi[1])) {
            bd[2] = bd[1]; bi[2] = bi[1];
            if (d < bd[0] || (d == bd[0] && i < bi[0])) {
                bd[1] = bd[0]; bi[1] = bi[0];
                bd[0] = d; bi[0] = i;
            } else { bd[1] = d; bi[1] = i; }
        } else { bd[2] = d; bi[2] = i; }
    }
}

// 64-bit xor-shuffle via two 32-bit shuffles
__device__ __forceinline__ unsigned long long shfl_xor_u64(unsigned long long v, int m) {
    unsigned lo = (unsigned)v, hi = (unsigned)(v >> 32);
    lo = __shfl_xor(lo, m, 64);
    hi = __shfl_xor(hi, m, 64);
    return ((unsigned long long)hi << 32) | lo;
}

// branchless insert into ascending sorted-3 of u64 (keep 3 smallest)
__device__ __forceinline__ void ins3u64(unsigned long long e,
                                        unsigned long long& t0,
                                        unsigned long long& t1,
                                        unsigned long long& t2) {
    unsigned long long a  = e < t2 ? e : t2;     // candidate enters bottom slot
    unsigned long long n2 = t1 > a ? t1 : a;
    unsigned long long n1 = t1 < a ? t1 : a;
    t2 = n2;
    unsigned long long m1 = t0 > n1 ? t0 : n1;
    t0 = t0 < n1 ? t0 : n1;
    t1 = m1;
}

__device__ __forceinline__ void stage16(const float* g, float* l) {
    __builtin_amdgcn_global_load_lds((const __attribute__((address_space(1))) void*)g,
                                     (__attribute__((address_space(3))) void*)l, 16, 0, 0);
}

// ---------------- pass 1: split-f16 MFMA + idx-embedded u32 top-2 trackers ----------------
// (R5-verified kernel, 62.4 us.) ONE barrier per super-tile; raw and conv double-buffered
// (LDS 75.6 KB -> 2 blocks/CU at 1024 thr). Pipeline per iter s:
//   barrier -> stage16(s+1)->raw[(s+1)&1] (async) -> conv(s): raw[s&1]->convb[s&1]
//          -> compute(s-1) from convb[(s-1)&1]
// acc = dot - xn/2 + 64 (bias via persistent z4 C-operand; acc in [23.5, 91] so uint order
// == float order). key = (bits(acc) & ~63) | (63 - tile): top-2 per (j,r) sub-stream via
// v_max/min_u32 (3 ops/elem + 1 and_or). Quantization 64 ulp affects only candidate
// pre-selection; pass2 refines top-8 with exact f32.
__global__ __attribute__((amdgpu_flat_work_group_size(P1T, P1T)))
__attribute__((amdgpu_waves_per_eu(4)))
void k_pass1(const float* __restrict__ train,
             const unsigned* __restrict__ scale_u,
             const _Float16* __restrict__ Qhi,
             const _Float16* __restrict__ Qlo,
             unsigned long long* __restrict__ cand) {
    __shared__ float s_inv[32];
    __shared__ __align__(16) float raw[2][RAWF];                     // 34560 B
    __shared__ __align__(16) unsigned char convb[2][NPT * TILE_B];   // 40960 B

    int tid = threadIdx.x;
    if (tid < 32) {
        float sc = __uint_as_float(scale_u[tid]);       // 0 for d>=27 (memset)
        s_inv[tid] = (sc != 0.f) ? 1.f / sc : 0.f;
    }
    int lane = tid & 63, w = tid >> 6;                  // w in [0,16)
    int l15 = lane & 15, quad = lane >> 4;

    h8 bhi[2], blo[2];
#pragma unroll
    for (int j = 0; j < 2; ++j) {
        int qt = w * 2 + j;                             // query tile 0..31
        size_t e = (size_t)(qt * 16 + l15) * 32 + quad * 8;
        bhi[j] = *(const h8*)(Qhi + e);
        blo[j] = *(const h8*)(Qlo + e);
    }

    // top-2 keys per (query-tile j, acc row r); 0 = -inf sentinel (real keys ~0x41BC.. +)
    unsigned kb0[2][4], kb1[2][4];
#pragma unroll
    for (int j = 0; j < 2; ++j)
#pragma unroll
        for (int r = 0; r < 4; ++r) { kb0[j][r] = 0u; kb1[j][r] = 0u; }

    const f4v z4 = {64.f, 64.f, 64.f, 64.f};            // persistent MFMA C bias (no per-j movs)

    int p0 = blockIdx.x * PTS_BLK;
    const float* gsup = train + (size_t)p0 * DIMS;   // 16B aligned (800*108 % 16 == 0)

    // async stage super-tile 0 (1024 threads: 4096 floats + 224 tail)
    {
        const float* gp = gsup; float* lp = raw[0];
        stage16(gp + tid * 4, lp + tid * 4);
        if (tid < 56) stage16(gp + 4096 + tid * 4, lp + 4096 + tid * 4);
    }

    for (int s = 0; s < NSUP; ++s) {
        __syncthreads();   // drains stage(s) vmcnt; raw[s&1] ready; convb[s&1] free (compute(s-2) done)

        if (s + 1 < NSUP) {   // async stage next super-tile; drains at next barrier
            const float* gp = gsup + (size_t)(s + 1) * RAWF;
            float* lp = raw[(s + 1) & 1];
            stage16(gp + tid * 4, lp + tid * 4);
            if (tid < 56) stage16(gp + 4096 + tid * 4, lp + 4096 + tid * 4);
        }

        // ---- conv(s): task = (point p, kblock gq of 8 dims); 640 tasks, waves 10..15 skip ----
        const float* rw = raw[s & 1];
        if (tid < PTS_SUP * 4) {
            int p = tid >> 2, gq = tid & 3;
            float x[8]; float part = 0.f;
#pragma unroll
            for (int i = 0; i < 8; ++i) {
                int d = gq * 8 + i;
                int dc = d < DIMS ? d : (DIMS - 1);     // clamp; s_inv[d>=27]=0 zeroes value
                float v = rw[p * DIMS + dc] * s_inv[d];
                x[i] = v;
                part = fmaf(v, v, part);
            }
            part += __shfl_xor(part, 1, 64);
            part += __shfl_xor(part, 2, 64);            // all 4 kblock-lanes hold xn
            h8 hv, lv;
#pragma unroll
            for (int i = 0; i < 8; ++i) {
                _Float16 h = (_Float16)x[i];
                hv[i] = h;
                lv[i] = (_Float16)(x[i] - (float)h);
            }
            if (gq == 3) {                              // slot i=3 is k=27: -xn/2 split
                float tt = -0.5f * part;
                _Float16 th = (_Float16)tt;
                hv[3] = th;
                lv[3] = (_Float16)(tt - (float)th);
            }
            unsigned char* dstb = convb[s & 1] + (p >> 4) * TILE_B + gq * 256 + (p & 15) * 16;
            *(h8*)dstb = hv;
            *(h8*)(dstb + 1024) = lv;
        }

        // ---- compute(s-1): 10 ptiles x 2 query-tiles x 3 MFMA + u32 top-2 update ----
        if (s > 0) {
            int ss = s - 1;
            const unsigned char* cb = convb[ss & 1];
            for (int t = 0; t < NPT; ++t) {
                const unsigned char* basep = cb + t * TILE_B;
                h8 ahi = *(const h8*)(basep + lane * 16);       // lane-linear: conflict-free
                h8 alo = *(const h8*)(basep + 1024 + lane * 16);
                unsigned ic = 63u - (unsigned)(ss * NPT + t);   // wave-uniform tile code (SGPR)
#pragma unroll
                for (int j = 0; j < 2; ++j) {
                    f4v acc;
                    acc = __builtin_amdgcn_mfma_f32_16x16x32_f16(alo, bhi[j], z4, 0, 0, 0);
                    acc = __builtin_amdgcn_mfma_f32_16x16x32_f16(ahi, blo[j], acc, 0, 0, 0);
                    acc = __builtin_amdgcn_mfma_f32_16x16x32_f16(ahi, bhi[j], acc, 0, 0, 0);
#pragma unroll
                    for (int r = 0; r < 4; ++r) {
                        unsigned key = (__float_as_uint(acc[r]) & 0xFFFFFFC0u) | ic;  // v_and_or_b32
                        unsigned b0 = kb0[j][r];
                        unsigned m  = key < b0 ? key : b0;          // v_min_u32
                        kb0[j][r]   = key > b0 ? key : b0;          // v_max_u32
                        unsigned b1 = kb1[j][r];
                        kb1[j][r]   = m > b1 ? m : b1;              // v_max_u32
                    }
                }
            }
        }
    }

    // epilogue: compute last super-tile
    __syncthreads();
    {
        int ss = NSUP - 1;
        const unsigned char* cb = convb[ss & 1];
        for (int t = 0; t < NPT; ++t) {
            const unsigned char* basep = cb + t * TILE_B;
            h8 ahi = *(const h8*)(basep + lane * 16);
            h8 alo = *(const h8*)(basep + 1024 + lane * 16);
            unsigned ic = 63u - (unsigned)(ss * NPT + t);
#pragma unroll
            for (int j = 0; j < 2; ++j) {
                f4v acc;
                acc = __builtin_amdgcn_mfma_f32_16x16x32_f16(alo, bhi[j], z4, 0, 0, 0);
                acc = __builtin_amdgcn_mfma_f32_16x16x32_f16(ahi, blo[j], acc, 0, 0, 0);
                acc = __builtin_amdgcn_mfma_f32_16x16x32_f16(ahi, bhi[j], acc, 0, 0, 0);
#pragma unroll
                for (int r = 0; r < 4; ++r) {
                    unsigned key = (__float_as_uint(acc[r]) & 0xFFFFFFC0u) | ic;
                    unsigned b0 = kb0[j][r];
                    unsigned m  = key < b0 ? key : b0;
                    kb0[j][r]   = key > b0 ? key : b0;
                    unsigned b1 = kb1[j][r];
                    kb1[j][r]   = m > b1 ? m : b1;
                }
            }
        }
    }

    // decode + cross-quad merge (4 disjoint point subsets per query) -> block top-3
    // sort64 = (~(key|63) << 32) | gidx : ascending u64 == exact lex (quantized d, idx)
    int g = blockIdx.x;
    int qr4 = quad * 4;
#pragma unroll
    for (int j = 0; j < 2; ++j) {
        unsigned long long t0 = U64MAX, t1 = U64MAX, t2 = U64MAX;
#pragma unroll
        for (int r = 0; r < 4; ++r) {
#pragma unroll
            for (int h = 0; h < 2; ++h) {
                unsigned k = h ? kb1[j][r] : kb0[j][r];
                unsigned tile = 63u - (k & 63u);
                unsigned gi = (unsigned)(p0 + (int)tile * 16 + qr4 + r);
                unsigned long long e = ((unsigned long long)(~(k | 63u)) << 32) | gi;
                ins3u64(e, t0, t1, t2);
            }
        }
#pragma unroll
        for (int step = 16; step <= 32; step <<= 1) {
            unsigned long long o0 = shfl_xor_u64(t0, step);
            unsigned long long o1 = shfl_xor_u64(t1, step);
            unsigned long long o2 = shfl_xor_u64(t2, step);
            ins3u64(o0, t0, t1, t2);
            ins3u64(o1, t0, t1, t2);
            ins3u64(o2, t0, t1, t2);
        }
        if (quad == 0) {
            int qq = (w * 2 + j) * 16 + l15;
            size_t off = (size_t)qq * NC + (size_t)g * KNN;
            cand[off + 0] = t0; cand[off + 1] = t1; cand[off + 2] = t2;
        }
    }
}

// branchless compare-exchange (ascending)
#define CE(a, b) do { unsigned long long lo_ = (a) < (b) ? (a) : (b); \
                      unsigned long long hi_ = (a) < (b) ? (b) : (a); \
                      (a) = lo_; (b) = hi_; } while (0)

// ---------------- pass 2: parallel u64 top-8 merge -> exact f32 refine -> vote ----------------
// 8 waves/query. cand entries are already ascending-packed u64 (approx-dist hi, idx lo);
// idx unique -> extraction pops exactly one lane.
__global__ __launch_bounds__(P2T) void k_pass2(const unsigned long long* __restrict__ cand,
                                               const float* __restrict__ train,
                                               const float* __restrict__ query,
                                               const unsigned* __restrict__ scale_u,
                                               const float* __restrict__ labels,
                                               float* __restrict__ out) {
    __shared__ unsigned long long smerge[64];   // 8 waves x top-8
    int q = blockIdx.x;
    int tid = threadIdx.x, lane = tid & 63, w = tid >> 6;
    const unsigned long long* cd = cand + (size_t)q * NC;

    // phase A: each thread owns <=3 candidates (1500 / 512); sort-3 (named regs, rule #20)
    unsigned long long c0 = cd[tid];
    unsigned long long c1 = cd[tid + P2T];
    unsigned long long c2 = (tid + 2 * P2T < NC) ? cd[tid + 2 * P2T] : U64MAX;
    CE(c0, c1); CE(c0, c2); CE(c1, c2);   // ascending

    // phase B: per-wave top-8 by repeated butterfly-u64-min extraction; lane 0 -> LDS
#pragma unroll
    for (int k = 0; k < 8; ++k) {
        unsigned long long m = c0;
#pragma unroll
        for (int st = 1; st < 64; st <<= 1) {
            unsigned long long o = shfl_xor_u64(m, st);
            if (o < m) m = o;
        }
        if (lane == 0) smerge[w * 8 + k] = m;
        bool win = (c0 == m);                 // exactly one lane (unique idx, m < U64MAX)
        c0 = win ? c1 : c0;
        c1 = win ? c2 : c1;
        c2 = win ? U64MAX : c2;
    }
    __syncthreads();
    if (w != 0) return;

    // phase C (wave 0): merge 8x8 wave winners -> global top-8; lane k keeps idx of rank k
    int myi = 0x7fffffff;
    {
        unsigned long long cur = smerge[lane];   // 64 real, unique entries
#pragma unroll
        for (int k = 0; k < 8; ++k) {
            unsigned long long m = cur;
#pragma unroll
            for (int st = 1; st < 64; st <<= 1) {
                unsigned long long o = shfl_xor_u64(m, st);
                if (o < m) m = o;
            }
            if (lane == k) myi = (int)(unsigned)m;
            if (cur == m) cur = U64MAX;
        }
    }

    // exact f32 scaled query + qn (same op order as the verified path)
    float inv[DIMS], qs_[DIMS], qn_ = 0.f;
#pragma unroll
    for (int d = 0; d < DIMS; ++d) {
        float sc = __uint_as_float(scale_u[d]);
        float iv = (sc != 0.f) ? 1.f / sc : 0.f;
        float v = query[(size_t)q * DIMS + d] * iv;
        inv[d] = iv; qs_[d] = v;
        qn_ = fmaf(v, v, qn_);
    }

    float myd2 = 3.4e38f;
    if (lane < 8) {
        const float* r = train + (size_t)myi * DIMS;
        float xnv = 0.f, dot = 0.f;
#pragma unroll
        for (int d = 0; d < DIMS; ++d) {
            float v = r[d] * inv[d];
            xnv = fmaf(v, v, xnv);
            dot = fmaf(qs_[d], v, dot);
        }
        myd2 = fmaf(-2.f, dot, qn_ + xnv);
    }

    float bd[KNN] = {3.4e38f, 3.4e38f, 3.4e38f};
    int   bi[KNN] = {0x7fffffff, 0x7fffffff, 0x7fffffff};
#pragma unroll
    for (int k = 0; k < 8; ++k) {
        float dk = __shfl(myd2, k, 64);
        int   ik = __shfl(myi, k, 64);
        insert3(dk, ik, bd, bi);
    }

    if (lane == 0) {
        float kd[KNN];
#pragma unroll
        for (int k = 0; k < KNN; ++k) kd[k] = sqrtf(fmaxf(bd[k], 0.f));
        float lab[KNN][NCLS];
#pragma unroll
        for (int k = 0; k < KNN; ++k) {
            const float* lr = labels + (size_t)bi[k] * NCLS;
#pragma unroll
            for (int c = 0; c < NCLS; ++c) lab[k][c] = lr[c];
        }
        float votes[NCLS];
#pragma unroll
        for (int c = 0; c < NCLS; ++c) votes[c] = 0.f;
#pragma unroll
        for (int k = 0; k < KNN; ++k) {
            float ks = (kd[k] == 0.f) ? 1.f : kd[k];
#pragma unroll
            for (int c = 0; c < NCLS; ++c) votes[c] += lab[k][c] / ks;
        }
        int best = 0; float bv = votes[0];
#pragma unroll
        for (int c = 1; c < NCLS; ++c) { if (votes[c] > bv) { bv = votes[c]; best = c; } }
        bool zero_hit = (kd[0] == 0.f);
#pragma unroll
        for (int k = 0; k < KNN; ++k) out[(size_t)q * KNN + k] = kd[k];
        float* ro = out + (size_t)BQ * KNN + (size_t)q * NCLS;
#pragma unroll
        for (int c = 0; c < NCLS; ++c)
            ro[c] = zero_hit ? lab[0][c] : ((c == best) ? 1.f : 0.f);
    }
}

extern "C" void kernel_launch(void* const* d_in, const int* in_sizes, int n_in,
                              void* d_out, int out_size, void* d_ws, size_t ws_size,
                              hipStream_t stream) {
    const float* query  = (const float*)d_in[0];
    const float* train  = (const float*)d_in[1];
    const float* labels = (const float*)d_in[2];
    float* out = (float*)d_out;

    // ws layout:
    //   [0)       scale_u: 32 u32 (128 B)
    //   [128)     Qhi: 512*32 f16 (32768 B)
    //   [32896)   Qlo: 512*32 f16 (32768 B)
    //   [65664)   cand: 512*1500 u64 (6144000 B)   total ~6.2 MB
    char* ws = (char*)d_ws;
    unsigned*  scale_u = (unsigned*)ws;
    _Float16*  Qhi = (_Float16*)(ws + 128);
    _Float16*  Qlo = (_Float16*)(ws + 32896);
    unsigned long long* cand = (unsigned long long*)(ws + 65664);

    hipMemsetAsync(ws, 0, 128, stream);  // zero scale accumulators
    k_scale<<<SCB, 256, 0, stream>>>(train, scale_u);
    k_qprep<<<8, 64, 0, stream>>>(query, scale_u, Qhi, Qlo);
    k_pass1<<<NB, P1T, 0, stream>>>(train, scale_u, Qhi, Qlo, cand);
    k_pass2<<<BQ, P2T, 0, stream>>>(cand, train, query, scale_u, labels, out);
}

// Round 14
// 169.108 us; speedup vs baseline: 3.1690x; 1.0102x over previous
//
#include <hip/hip_runtime.h>
#include <math.h>

typedef _Float16 h8 __attribute__((ext_vector_type(8)));
typedef float    f4v __attribute__((ext_vector_type(4)));

#define N_TRAIN 400000
#define DIMS    27
#define BQ      512
#define NCLS    11
#define KNN     3
#define NB      500            // pass-1 blocks
#define P1T     1024           // pass-1 threads (16 waves)
#define PTS_BLK 800            // points per block (500*800 = 400000 exact)
#define PTS_SUP 160            // points per super-tile
#define NSUP    5
#define NPT     10
#define RAWF    4320           // floats per super-tile (160*27)
#define TILE_B  2048           // conv bytes per ptile: hi 1024 + lo 1024
#define NC      (NB * KNN)     // candidates per query (1500)
#define SCB     391            // k_scale blocks (391*256 = 100096 >= 100000 groups of 4 rows)
#define P2T     512            // pass-2 threads (8 waves)

#define U64MAX 0xFFFFFFFFFFFFFFFFULL

// ---------------- scale = max(|train|, axis=0) — register-resident, no LDS staging ----------------
// (R6-verified kernel.) Each thread owns 4 CONTIGUOUS rows = 108 floats = 27 uint4 (16B aligned:
// g*432 % 16 == 0). Column of float e of uint4 k is (4k+e) % 27 — compile-time under full unroll,
// so the 27 per-thread maxes live in registers (rule #20). fmaxf(m, fabsf(x)) folds to v_max |x|.
__global__ __launch_bounds__(256) void k_scale(const float* __restrict__ train,
                                               unsigned* __restrict__ scale_u) {
    __shared__ float red[4][DIMS];
    int tid = threadIdx.x;
    int lane = tid & 63, w = tid >> 6;
    int g = blockIdx.x * 256 + tid;            // 4-row group id
    float m[DIMS];
#pragma unroll
    for (int d = 0; d < DIMS; ++d) m[d] = 0.f;
    if (g < N_TRAIN / 4) {
        const uint4* p = (const uint4*)(train + (size_t)g * (4 * DIMS));
#pragma unroll
        for (int k = 0; k < DIMS; ++k) {
            uint4 v = p[k];
            m[(4 * k + 0) % DIMS] = fmaxf(m[(4 * k + 0) % DIMS], fabsf(__uint_as_float(v.x)));
            m[(4 * k + 1) % DIMS] = fmaxf(m[(4 * k + 1) % DIMS], fabsf(__uint_as_float(v.y)));
            m[(4 * k + 2) % DIMS] = fmaxf(m[(4 * k + 2) % DIMS], fabsf(__uint_as_float(v.z)));
            m[(4 * k + 3) % DIMS] = fmaxf(m[(4 * k + 3) % DIMS], fabsf(__uint_as_float(v.w)));
        }
    }
    // wave butterfly reduce (27 dims x 6 steps)
#pragma unroll
    for (int d = 0; d < DIMS; ++d) {
        float t = m[d];
#pragma unroll
        for (int st = 1; st < 64; st <<= 1) t = fmaxf(t, __shfl_xor(t, st, 64));
        m[d] = t;
    }
    if (lane == 0) {
#pragma unroll
        for (int d = 0; d < DIMS; ++d) red[w][d] = m[d];
    }
    __syncthreads();
    if (tid < DIMS) {
        float v = fmaxf(fmaxf(red[0][tid], red[1][tid]), fmaxf(red[2][tid], red[3][tid]));
        atomicMax(&scale_u[tid], __float_as_uint(v)); // values >= 0: uint order == float order
    }
}

// ---------------- query prep: split-f16 B-fragments, k=27 slot = {1,0} ----------------
__global__ __launch_bounds__(64) void k_qprep(const float* __restrict__ query,
                                              const unsigned* __restrict__ scale_u,
                                              _Float16* __restrict__ Qhi,
                                              _Float16* __restrict__ Qlo) {
    int q = blockIdx.x * 64 + threadIdx.x;
    if (q >= BQ) return;
    const float* r = query + (size_t)q * DIMS;
#pragma unroll
    for (int d = 0; d < 32; ++d) {
        _Float16 hi = (_Float16)0.f, lo = (_Float16)0.f;
        if (d < DIMS) {
            float sc = __uint_as_float(scale_u[d]);
            float inv = (sc != 0.f) ? 1.f / sc : 0.f;   // divide_no_nan
            float xs = r[d] * inv;
            hi = (_Float16)xs;
            lo = (_Float16)(xs - (float)hi);
        } else if (d == 27) {
            hi = (_Float16)1.f;   // multiplies A's -xn/2 hi+lo slots
        }
        Qhi[q * 32 + d] = hi;
        Qlo[q * 32 + d] = lo;
    }
}

// lexicographic (key, idx) insert into ascending sorted triple — matches top_k ties
__device__ __forceinline__ void insert3(float d, int i, float* bd, int* bi) {
    if (d < bd[2] || (d == bd[2] && i < bi[2])) {
        if (d < bd[1] || (d == bd[1] && i < bi[1])) {
            bd[2] = bd[1]; bi[2] = bi[1];
            if (d < bd[0] || (d == bd[0] && i < bi[0])) {
                bd[1] = bd[0]; bi[1] = bi[0];
                bd[0] = d; bi[0] = i;
            } else { bd[1] = d; bi[1] = i; }
        } else { bd[2] = d; bi[2] = i; }
    }
}

// 64-bit xor-shuffle via two 32-bit shuffles
__device__ __forceinline__ unsigned long long shfl_xor_u64(unsigned long long v, int m) {
    unsigned lo = (unsigned)v, hi = (unsigned)(v >> 32);
    lo = __shfl_xor(lo, m, 64);
    hi = __shfl_xor(hi, m, 64);
    return ((unsigned long long)hi << 32) | lo;
}

// branchless insert into ascending sorted-3 of u64 (keep 3 smallest)
__device__ __forceinline__ void ins3u64(unsigned long long e,
                                        unsigned long long& t0,
                                        unsigned long long& t1,
                                        unsigned long long& t2) {
    unsigned long long a  = e < t2 ? e : t2;     // candidate enters bottom slot
    unsigned long long n2 = t1 > a ? t1 : a;
    unsigned long long n1 = t1 < a ? t1 : a;
    t2 = n2;
    unsigned long long m1 = t0 > n1 ? t0 : n1;
    t0 = t0 < n1 ? t0 : n1;
    t1 = m1;
}

__device__ __forceinline__ void stage16(const float* g, float* l) {
    __builtin_amdgcn_global_load_lds((const __attribute__((address_space(1))) void*)g,
                                     (__attribute__((address_space(3))) void*)l, 16, 0, 0);
}

// ---------------- pass 1: split-f16 MFMA + idx-embedded u32 top-2 trackers ----------------
// (R5/R13-verified structure, 62-65 us.) ONE barrier per super-tile; raw and conv double-buffered
// (LDS 75.6 KB -> 2 blocks/CU at 1024 thr). Pipeline per iter s:
//   barrier -> stage16(s+1)->raw[(s+1)&1] (async) -> conv(s): raw[s&1]->convb[s&1]
//          -> compute(s-1) from convb[(s-1)&1]
// acc = dot - xn/2 + 64 (bias via persistent z4 C-operand; acc in [23.5, 91] so uint order
// == float order). key = (bits(acc) & ~63) | (63 - tile).
// R14 tracker: top-2 insert via v_med3_u32 — with the invariant kb0 >= kb1,
//   kb1' = med3(key, kb0, kb1); kb0' = max(key, kb0)   (3 VALU ops/elem vs 4).
// Exact (keys within a stream are distinct: tile codes differ). s_setprio(1) wraps each
// MFMA triple (T5; wave role-split: conv waves 0..9 vs compute-bound waves 10..15).
__global__ __attribute__((amdgpu_flat_work_group_size(P1T, P1T)))
__attribute__((amdgpu_waves_per_eu(4)))
void k_pass1(const float* __restrict__ train,
             const unsigned* __restrict__ scale_u,
             const _Float16* __restrict__ Qhi,
             const _Float16* __restrict__ Qlo,
             unsigned long long* __restrict__ cand) {
    __shared__ float s_inv[32];
    __shared__ __align__(16) float raw[2][RAWF];                     // 34560 B
    __shared__ __align__(16) unsigned char convb[2][NPT * TILE_B];   // 40960 B

    int tid = threadIdx.x;
    if (tid < 32) {
        float sc = __uint_as_float(scale_u[tid]);       // 0 for d>=27 (memset)
        s_inv[tid] = (sc != 0.f) ? 1.f / sc : 0.f;
    }
    int lane = tid & 63, w = tid >> 6;                  // w in [0,16)
    int l15 = lane & 15, quad = lane >> 4;

    h8 bhi[2], blo[2];
#pragma unroll
    for (int j = 0; j < 2; ++j) {
        int qt = w * 2 + j;                             // query tile 0..31
        size_t e = (size_t)(qt * 16 + l15) * 32 + quad * 8;
        bhi[j] = *(const h8*)(Qhi + e);
        blo[j] = *(const h8*)(Qlo + e);
    }

    // top-2 keys per (query-tile j, acc row r); 0 = -inf sentinel (real keys ~0x41BC.. +)
    unsigned kb0[2][4], kb1[2][4];
#pragma unroll
    for (int j = 0; j < 2; ++j)
#pragma unroll
        for (int r = 0; r < 4; ++r) { kb0[j][r] = 0u; kb1[j][r] = 0u; }

    const f4v z4 = {64.f, 64.f, 64.f, 64.f};            // persistent MFMA C bias (no per-j movs)

    int p0 = blockIdx.x * PTS_BLK;
    const float* gsup = train + (size_t)p0 * DIMS;   // 16B aligned (800*108 % 16 == 0)

    // async stage super-tile 0 (1024 threads: 4096 floats + 224 tail)
    {
        const float* gp = gsup; float* lp = raw[0];
        stage16(gp + tid * 4, lp + tid * 4);
        if (tid < 56) stage16(gp + 4096 + tid * 4, lp + 4096 + tid * 4);
    }

    for (int s = 0; s < NSUP; ++s) {
        __syncthreads();   // drains stage(s) vmcnt; raw[s&1] ready; convb[s&1] free (compute(s-2) done)

        if (s + 1 < NSUP) {   // async stage next super-tile; drains at next barrier
            const float* gp = gsup + (size_t)(s + 1) * RAWF;
            float* lp = raw[(s + 1) & 1];
            stage16(gp + tid * 4, lp + tid * 4);
            if (tid < 56) stage16(gp + 4096 + tid * 4, lp + 4096 + tid * 4);
        }

        // ---- conv(s): task = (point p, kblock gq of 8 dims); 640 tasks, waves 10..15 skip ----
        const float* rw = raw[s & 1];
        if (tid < PTS_SUP * 4) {
            int p = tid >> 2, gq = tid & 3;
            float x[8]; float part = 0.f;
#pragma unroll
            for (int i = 0; i < 8; ++i) {
                int d = gq * 8 + i;
                int dc = d < DIMS ? d : (DIMS - 1);     // clamp; s_inv[d>=27]=0 zeroes value
                float v = rw[p * DIMS + dc] * s_inv[d];
                x[i] = v;
                part = fmaf(v, v, part);
            }
            part += __shfl_xor(part, 1, 64);
            part += __shfl_xor(part, 2, 64);            // all 4 kblock-lanes hold xn
            h8 hv, lv;
#pragma unroll
            for (int i = 0; i < 8; ++i) {
                _Float16 h = (_Float16)x[i];
                hv[i] = h;
                lv[i] = (_Float16)(x[i] - (float)h);
            }
            if (gq == 3) {                              // slot i=3 is k=27: -xn/2 split
                float tt = -0.5f * part;
                _Float16 th = (_Float16)tt;
                hv[3] = th;
                lv[3] = (_Float16)(tt - (float)th);
            }
            unsigned char* dstb = convb[s & 1] + (p >> 4) * TILE_B + gq * 256 + (p & 15) * 16;
            *(h8*)dstb = hv;
            *(h8*)(dstb + 1024) = lv;
        }

        // ---- compute(s-1): 10 ptiles x 2 query-tiles x 3 MFMA + med3 top-2 update ----
        if (s > 0) {
            int ss = s - 1;
            const unsigned char* cb = convb[ss & 1];
            for (int t = 0; t < NPT; ++t) {
                const unsigned char* basep = cb + t * TILE_B;
                h8 ahi = *(const h8*)(basep + lane * 16);       // lane-linear: conflict-free
                h8 alo = *(const h8*)(basep + 1024 + lane * 16);
                unsigned ic = 63u - (unsigned)(ss * NPT + t);   // wave-uniform tile code (SGPR)
#pragma unroll
                for (int j = 0; j < 2; ++j) {
                    f4v acc;
                    __builtin_amdgcn_s_setprio(1);
                    acc = __builtin_amdgcn_mfma_f32_16x16x32_f16(alo, bhi[j], z4, 0, 0, 0);
                    acc = __builtin_amdgcn_mfma_f32_16x16x32_f16(ahi, blo[j], acc, 0, 0, 0);
                    acc = __builtin_amdgcn_mfma_f32_16x16x32_f16(ahi, bhi[j], acc, 0, 0, 0);
                    __builtin_amdgcn_s_setprio(0);
#pragma unroll
                    for (int r = 0; r < 4; ++r) {
                        unsigned key = (__float_as_uint(acc[r]) & 0xFFFFFFC0u) | ic;  // v_and_or_b32
                        unsigned nb1;
                        asm("v_med3_u32 %0, %1, %2, %3"
                            : "=v"(nb1) : "v"(key), "v"(kb0[j][r]), "v"(kb1[j][r]));
                        kb0[j][r] = key > kb0[j][r] ? key : kb0[j][r];  // v_max_u32
                        kb1[j][r] = nb1;
                    }
                }
            }
        }
    }

    // epilogue: compute last super-tile
    __syncthreads();
    {
        int ss = NSUP - 1;
        const unsigned char* cb = convb[ss & 1];
        for (int t = 0; t < NPT; ++t) {
            const unsigned char* basep = cb + t * TILE_B;
            h8 ahi = *(const h8*)(basep + lane * 16);
            h8 alo = *(const h8*)(basep + 1024 + lane * 16);
            unsigned ic = 63u - (unsigned)(ss * NPT + t);
#pragma unroll
            for (int j = 0; j < 2; ++j) {
                f4v acc;
                __builtin_amdgcn_s_setprio(1);
                acc = __builtin_amdgcn_mfma_f32_16x16x32_f16(alo, bhi[j], z4, 0, 0, 0);
                acc = __builtin_amdgcn_mfma_f32_16x16x32_f16(ahi, blo[j], acc, 0, 0, 0);
                acc = __builtin_amdgcn_mfma_f32_16x16x32_f16(ahi, bhi[j], acc, 0, 0, 0);
                __builtin_amdgcn_s_setprio(0);
#pragma unroll
                for (int r = 0; r < 4; ++r) {
                    unsigned key = (__float_as_uint(acc[r]) & 0xFFFFFFC0u) | ic;
                    unsigned nb1;
                    asm("v_med3_u32 %0, %1, %2, %3"
                        : "=v"(nb1) : "v"(key), "v"(kb0[j][r]), "v"(kb1[j][r]));
                    kb0[j][r] = key > kb0[j][r] ? key : kb0[j][r];
                    kb1[j][r] = nb1;
                }
            }
        }
    }

    // decode + cross-quad merge (4 disjoint point subsets per query) -> block top-3
    // sort64 = (~(key|63) << 32) | gidx : ascending u64 == exact lex (quantized d, idx)
    int g = blockIdx.x;
    int qr4 = quad * 4;
#pragma unroll
    for (int j = 0; j < 2; ++j) {
        unsigned long long t0 = U64MAX, t1 = U64MAX, t2 = U64MAX;
#pragma unroll
        for (int r = 0; r < 4; ++r) {
#pragma unroll
            for (int h = 0; h < 2; ++h) {
                unsigned k = h ? kb1[j][r] : kb0[j][r];
                unsigned tile = 63u - (k & 63u);
                unsigned gi = (unsigned)(p0 + (int)tile * 16 + qr4 + r);
                unsigned long long e = ((unsigned long long)(~(k | 63u)) << 32) | gi;
                ins3u64(e, t0, t1, t2);
            }
        }
#pragma unroll
        for (int step = 16; step <= 32; step <<= 1) {
            unsigned long long o0 = shfl_xor_u64(t0, step);
            unsigned long long o1 = shfl_xor_u64(t1, step);
            unsigned long long o2 = shfl_xor_u64(t2, step);
            ins3u64(o0, t0, t1, t2);
            ins3u64(o1, t0, t1, t2);
            ins3u64(o2, t0, t1, t2);
        }
        if (quad == 0) {
            int qq = (w * 2 + j) * 16 + l15;
            size_t off = (size_t)qq * NC + (size_t)g * KNN;
            cand[off + 0] = t0; cand[off + 1] = t1; cand[off + 2] = t2;
        }
    }
}

// branchless compare-exchange (ascending)
#define CE(a, b) do { unsigned long long lo_ = (a) < (b) ? (a) : (b); \
                      unsigned long long hi_ = (a) < (b) ? (b) : (a); \
                      (a) = lo_; (b) = hi_; } while (0)

// ---------------- pass 2: parallel u64 top-8 merge -> exact f32 refine -> vote ----------------
// 8 waves/query. cand entries are already ascending-packed u64 (approx-dist hi, idx lo);
// idx unique -> extraction pops exactly one lane.
__global__ __launch_bounds__(P2T) void k_pass2(const unsigned long long* __restrict__ cand,
                                               const float* __restrict__ train,
                                               const float* __restrict__ query,
                                               const unsigned* __restrict__ scale_u,
                                               const float* __restrict__ labels,
                                               float* __restrict__ out) {
    __shared__ unsigned long long smerge[64];   // 8 waves x top-8
    int q = blockIdx.x;
    int tid = threadIdx.x, lane = tid & 63, w = tid >> 6;
    const unsigned long long* cd = cand + (size_t)q * NC;

    // phase A: each thread owns <=3 candidates (1500 / 512); sort-3 (named regs, rule #20)
    unsigned long long c0 = cd[tid];
    unsigned long long c1 = cd[tid + P2T];
    unsigned long long c2 = (tid + 2 * P2T < NC) ? cd[tid + 2 * P2T] : U64MAX;
    CE(c0, c1); CE(c0, c2); CE(c1, c2);   // ascending

    // phase B: per-wave top-8 by repeated butterfly-u64-min extraction; lane 0 -> LDS
#pragma unroll
    for (int k = 0; k < 8; ++k) {
        unsigned long long m = c0;
#pragma unroll
        for (int st = 1; st < 64; st <<= 1) {
            unsigned long long o = shfl_xor_u64(m, st);
            if (o < m) m = o;
        }
        if (lane == 0) smerge[w * 8 + k] = m;
        bool win = (c0 == m);                 // exactly one lane (unique idx, m < U64MAX)
        c0 = win ? c1 : c0;
        c1 = win ? c2 : c1;
        c2 = win ? U64MAX : c2;
    }
    __syncthreads();
    if (w != 0) return;

    // phase C (wave 0): merge 8x8 wave winners -> global top-8; lane k keeps idx of rank k
    int myi = 0x7fffffff;
    {
        unsigned long long cur = smerge[lane];   // 64 real, unique entries
#pragma unroll
        for (int k = 0; k < 8; ++k) {
            unsigned long long m = cur;
#pragma unroll
            for (int st = 1; st < 64; st <<= 1) {
                unsigned long long o = shfl_xor_u64(m, st);
                if (o < m) m = o;
            }
            if (lane == k) myi = (int)(unsigned)m;
            if (cur == m) cur = U64MAX;
        }
    }

    // exact f32 scaled query + qn (same op order as the verified path)
    float inv[DIMS], qs_[DIMS], qn_ = 0.f;
#pragma unroll
    for (int d = 0; d < DIMS; ++d) {
        float sc = __uint_as_float(scale_u[d]);
        float iv = (sc != 0.f) ? 1.f / sc : 0.f;
        float v = query[(size_t)q * DIMS + d] * iv;
        inv[d] = iv; qs_[d] = v;
        qn_ = fmaf(v, v, qn_);
    }

    float myd2 = 3.4e38f;
    if (lane < 8) {
        const float* r = train + (size_t)myi * DIMS;
        float xnv = 0.f, dot = 0.f;
#pragma unroll
        for (int d = 0; d < DIMS; ++d) {
            float v = r[d] * inv[d];
            xnv = fmaf(v, v, xnv);
            dot = fmaf(qs_[d], v, dot);
        }
        myd2 = fmaf(-2.f, dot, qn_ + xnv);
    }

    float bd[KNN] = {3.4e38f, 3.4e38f, 3.4e38f};
    int   bi[KNN] = {0x7fffffff, 0x7fffffff, 0x7fffffff};
#pragma unroll
    for (int k = 0; k < 8; ++k) {
        float dk = __shfl(myd2, k, 64);
        int   ik = __shfl(myi, k, 64);
        insert3(dk, ik, bd, bi);
    }

    if (lane == 0) {
        float kd[KNN];
#pragma unroll
        for (int k = 0; k < KNN; ++k) kd[k] = sqrtf(fmaxf(bd[k], 0.f));
        float lab[KNN][NCLS];
#pragma unroll
        for (int k = 0; k < KNN; ++k) {
            const float* lr = labels + (size_t)bi[k] * NCLS;
#pragma unroll
            for (int c = 0; c < NCLS; ++c) lab[k][c] = lr[c];
        }
        float votes[NCLS];
#pragma unroll
        for (int c = 0; c < NCLS; ++c) votes[c] = 0.f;
#pragma unroll
        for (int k = 0; k < KNN; ++k) {
            float ks = (kd[k] == 0.f) ? 1.f : kd[k];
#pragma unroll
            for (int c = 0; c < NCLS; ++c) votes[c] += lab[k][c] / ks;
        }
        int best = 0; float bv = votes[0];
#pragma unroll
        for (int c = 1; c < NCLS; ++c) { if (votes[c] > bv) { bv = votes[c]; best = c; } }
        bool zero_hit = (kd[0] == 0.f);
#pragma unroll
        for (int k = 0; k < KNN; ++k) out[(size_t)q * KNN + k] = kd[k];
        float* ro = out + (size_t)BQ * KNN + (size_t)q * NCLS;
#pragma unroll
        for (int c = 0; c < NCLS; ++c)
            ro[c] = zero_hit ? lab[0][c] : ((c == best) ? 1.f : 0.f);
    }
}

extern "C" void kernel_launch(void* const* d_in, const int* in_sizes, int n_in,
                              void* d_out, int out_size, void* d_ws, size_t ws_size,
                              hipStream_t stream) {
    const float* query  = (const float*)d_in[0];
    const float* train  = (const float*)d_in[1];
    const float* labels = (const float*)d_in[2];
    float* out = (float*)d_out;

    // ws layout:
    //   [0)       scale_u: 32 u32 (128 B)
    //   [128)     Qhi: 512*32 f16 (32768 B)
    //   [32896)   Qlo: 512*32 f16 (32768 B)
    //   [65664)   cand: 512*1500 u64 (6144000 B)   total ~6.2 MB
    char* ws = (char*)d_ws;
    unsigned*  scale_u = (unsigned*)ws;
    _Float16*  Qhi = (_Float16*)(ws + 128);
    _Float16*  Qlo = (_Float16*)(ws + 32896);
    unsigned long long* cand = (unsigned long long*)(ws + 65664);

    hipMemsetAsync(ws, 0, 128, stream);  // zero scale accumulators
    k_scale<<<SCB, 256, 0, stream>>>(train, scale_u);
    k_qprep<<<8, 64, 0, stream>>>(query, scale_u, Qhi, Qlo);
    k_pass1<<<NB, P1T, 0, stream>>>(train, scale_u, Qhi, Qlo, cand);
    k_pass2<<<BQ, P2T, 0, stream>>>(cand, train, query, scale_u, labels, out);
}

// Round 15
// 164.736 us; speedup vs baseline: 3.2531x; 1.0265x over previous
//
#include <hip/hip_runtime.h>
#include <math.h>

typedef _Float16 h8 __attribute__((ext_vector_type(8)));
typedef float    f4v __attribute__((ext_vector_type(4)));

#define N_TRAIN 400000
#define DIMS    27
#define BQ      512
#define NCLS    11
#define KNN     3
#define NB      500            // pass-1 blocks
#define P1T     1024           // pass-1 threads (16 waves)
#define PTS_BLK 800            // points per block (500*800 = 400000 exact)
#define PTS_SUP 160            // points per super-tile
#define NSUP    5
#define NPT     10
#define RAWF    4320           // floats per super-tile (160*27)
#define TILE_B  1024           // conv bytes per ptile (hi fragments only; lo dropped)
#define NC      (NB * KNN)     // candidates per query (1500)
#define SCB     391            // k_scale blocks (391*256 = 100096 >= 100000 groups of 4 rows)
#define P2T     512            // pass-2 threads (8 waves)

#define U64MAX 0xFFFFFFFFFFFFFFFFULL

// ---------------- scale = max(|train|, axis=0) — register-resident, no LDS staging ----------------
// (R6-verified kernel.)
__global__ __launch_bounds__(256) void k_scale(const float* __restrict__ train,
                                               unsigned* __restrict__ scale_u) {
    __shared__ float red[4][DIMS];
    int tid = threadIdx.x;
    int lane = tid & 63, w = tid >> 6;
    int g = blockIdx.x * 256 + tid;            // 4-row group id
    float m[DIMS];
#pragma unroll
    for (int d = 0; d < DIMS; ++d) m[d] = 0.f;
    if (g < N_TRAIN / 4) {
        const uint4* p = (const uint4*)(train + (size_t)g * (4 * DIMS));
#pragma unroll
        for (int k = 0; k < DIMS; ++k) {
            uint4 v = p[k];
            m[(4 * k + 0) % DIMS] = fmaxf(m[(4 * k + 0) % DIMS], fabsf(__uint_as_float(v.x)));
            m[(4 * k + 1) % DIMS] = fmaxf(m[(4 * k + 1) % DIMS], fabsf(__uint_as_float(v.y)));
            m[(4 * k + 2) % DIMS] = fmaxf(m[(4 * k + 2) % DIMS], fabsf(__uint_as_float(v.z)));
            m[(4 * k + 3) % DIMS] = fmaxf(m[(4 * k + 3) % DIMS], fabsf(__uint_as_float(v.w)));
        }
    }
#pragma unroll
    for (int d = 0; d < DIMS; ++d) {           // wave butterfly (27 dims x 6 steps)
        float t = m[d];
#pragma unroll
        for (int st = 1; st < 64; st <<= 1) t = fmaxf(t, __shfl_xor(t, st, 64));
        m[d] = t;
    }
    if (lane == 0) {
#pragma unroll
        for (int d = 0; d < DIMS; ++d) red[w][d] = m[d];
    }
    __syncthreads();
    if (tid < DIMS) {
        float v = fmaxf(fmaxf(red[0][tid], red[1][tid]), fmaxf(red[2][tid], red[3][tid]));
        atomicMax(&scale_u[tid], __float_as_uint(v)); // values >= 0: uint order == float order
    }
}

// ---------------- query prep: split-f16 B-fragments, k=27 slot = {1,0} ----------------
__global__ __launch_bounds__(64) void k_qprep(const float* __restrict__ query,
                                              const unsigned* __restrict__ scale_u,
                                              _Float16* __restrict__ Qhi,
                                              _Float16* __restrict__ Qlo) {
    int q = blockIdx.x * 64 + threadIdx.x;
    if (q >= BQ) return;
    const float* r = query + (size_t)q * DIMS;
#pragma unroll
    for (int d = 0; d < 32; ++d) {
        _Float16 hi = (_Float16)0.f, lo = (_Float16)0.f;
        if (d < DIMS) {
            float sc = __uint_as_float(scale_u[d]);
            float inv = (sc != 0.f) ? 1.f / sc : 0.f;   // divide_no_nan
            float xs = r[d] * inv;
            hi = (_Float16)xs;
            lo = (_Float16)(xs - (float)hi);
        } else if (d == 27) {
            hi = (_Float16)1.f;   // A slot 27 is 0 now (xn folded via C-init); term is 0 either way
        }
        Qhi[q * 32 + d] = hi;
        Qlo[q * 32 + d] = lo;
    }
}

// lexicographic (key, idx) insert into ascending sorted triple — matches top_k ties
__device__ __forceinline__ void insert3(float d, int i, float* bd, int* bi) {
    if (d < bd[2] || (d == bd[2] && i < bi[2])) {
        if (d < bd[1] || (d == bd[1] && i < bi[1])) {
            bd[2] = bd[1]; bi[2] = bi[1];
            if (d < bd[0] || (d == bd[0] && i < bi[0])) {
                bd[1] = bd[0]; bi[1] = bi[0];
                bd[0] = d; bi[0] = i;
            } else { bd[1] = d; bi[1] = i; }
        } else { bd[2] = d; bi[2] = i; }
    }
}

// 64-bit xor-shuffle via two 32-bit shuffles
__device__ __forceinline__ unsigned long long shfl_xor_u64(unsigned long long v, int m) {
    unsigned lo = (unsigned)v, hi = (unsigned)(v >> 32);
    lo = __shfl_xor(lo, m, 64);
    hi = __shfl_xor(hi, m, 64);
    return ((unsigned long long)hi << 32) | lo;
}

// branchless insert into ascending sorted-3 of u64 (keep 3 smallest)
__device__ __forceinline__ void ins3u64(unsigned long long e,
                                        unsigned long long& t0,
                                        unsigned long long& t1,
                                        unsigned long long& t2) {
    unsigned long long a  = e < t2 ? e : t2;     // candidate enters bottom slot
    unsigned long long n2 = t1 > a ? t1 : a;
    unsigned long long n1 = t1 < a ? t1 : a;
    t2 = n2;
    unsigned long long m1 = t0 > n1 ? t0 : n1;
    t0 = t0 < n1 ? t0 : n1;
    t1 = m1;
}

__device__ __forceinline__ void stage16(const float* g, float* l) {
    __builtin_amdgcn_global_load_lds((const __attribute__((address_space(1))) void*)g,
                                     (__attribute__((address_space(3))) void*)l, 16, 0, 0);
}

// ---------------- pass 1: hi-f16 MFMA (train-lo dropped) + exact-f32 xn via C-init ----------------
// R15 numerics: dot approx = ah·bh + ah·bl (train-side lo dropped; error ~1e-3 on acc, vs the
// ~0.1 d^2 interloper margin of the top-8 refine). xn is now EXACT: conv stores
// xnh[p] = 64 - xn/2 (f32, includes the +64 uint-order bias); compute loads 4 consecutive
// points' xnh as the MFMA C-init (ds_read_b128, row=quad*4+r matches C layout row).
// Per tile: 2 ds_read + 4 MFMA (was 6) + med3 trackers. conv: no lo-split (half the work,
// half the LDS). LDS 56.5 KB -> still 2 blocks/CU. Everything else R14-verified.
__global__ __attribute__((amdgpu_flat_work_group_size(P1T, P1T)))
__attribute__((amdgpu_waves_per_eu(4)))
void k_pass1(const float* __restrict__ train,
             const unsigned* __restrict__ scale_u,
             const _Float16* __restrict__ Qhi,
             const _Float16* __restrict__ Qlo,
             unsigned long long* __restrict__ cand) {
    __shared__ float s_inv[32];
    __shared__ __align__(16) float raw[2][RAWF];                     // 34560 B
    __shared__ __align__(16) unsigned char convb[2][NPT * TILE_B];   // 20480 B
    __shared__ __align__(16) float xnhb[2][NPT * 16];                // 1280 B (xn C-init per point)

    int tid = threadIdx.x;
    if (tid < 32) {
        float sc = __uint_as_float(scale_u[tid]);       // 0 for d>=27 (memset)
        s_inv[tid] = (sc != 0.f) ? 1.f / sc : 0.f;
    }
    int lane = tid & 63, w = tid >> 6;                  // w in [0,16)
    int l15 = lane & 15, quad = lane >> 4;

    h8 bhi[2], blo[2];
#pragma unroll
    for (int j = 0; j < 2; ++j) {
        int qt = w * 2 + j;                             // query tile 0..31
        size_t e = (size_t)(qt * 16 + l15) * 32 + quad * 8;
        bhi[j] = *(const h8*)(Qhi + e);
        blo[j] = *(const h8*)(Qlo + e);
    }

    // top-2 keys per (query-tile j, acc row r); 0 = -inf sentinel (real keys ~0x41BC.. +)
    unsigned kb0[2][4], kb1[2][4];
#pragma unroll
    for (int j = 0; j < 2; ++j)
#pragma unroll
        for (int r = 0; r < 4; ++r) { kb0[j][r] = 0u; kb1[j][r] = 0u; }

    int p0 = blockIdx.x * PTS_BLK;
    const float* gsup = train + (size_t)p0 * DIMS;   // 16B aligned (800*108 % 16 == 0)

    // async stage super-tile 0 (1024 threads: 4096 floats + 224 tail)
    {
        const float* gp = gsup; float* lp = raw[0];
        stage16(gp + tid * 4, lp + tid * 4);
        if (tid < 56) stage16(gp + 4096 + tid * 4, lp + 4096 + tid * 4);
    }

    for (int s = 0; s < NSUP; ++s) {
        __syncthreads();   // drains stage(s) vmcnt; raw[s&1] ready; convb[s&1] free (compute(s-2) done)

        if (s + 1 < NSUP) {   // async stage next super-tile; drains at next barrier
            const float* gp = gsup + (size_t)(s + 1) * RAWF;
            float* lp = raw[(s + 1) & 1];
            stage16(gp + tid * 4, lp + tid * 4);
            if (tid < 56) stage16(gp + 4096 + tid * 4, lp + 4096 + tid * 4);
        }

        // ---- conv(s): task = (point p, kblock gq of 8 dims); 640 tasks, waves 10..15 skip ----
        const float* rw = raw[s & 1];
        if (tid < PTS_SUP * 4) {
            int p = tid >> 2, gq = tid & 3;
            float x[8]; float part = 0.f;
#pragma unroll
            for (int i = 0; i < 8; ++i) {
                int d = gq * 8 + i;
                int dc = d < DIMS ? d : (DIMS - 1);     // clamp; s_inv[d>=27]=0 zeroes value
                float v = rw[p * DIMS + dc] * s_inv[d]; // (d==27 -> 0 -> hv[3]==0 naturally)
                x[i] = v;
                part = fmaf(v, v, part);
            }
            part += __shfl_xor(part, 1, 64);
            part += __shfl_xor(part, 2, 64);            // all 4 kblock-lanes hold xn
            h8 hv;
#pragma unroll
            for (int i = 0; i < 8; ++i) hv[i] = (_Float16)x[i];
            if (gq == 3)                                // one lane per point: exact f32 xn + bias
                xnhb[s & 1][p] = fmaf(-0.5f, part, 64.f);
            unsigned char* dstb = convb[s & 1] + (p >> 4) * TILE_B + gq * 256 + (p & 15) * 16;
            *(h8*)dstb = hv;
        }

        // ---- compute(s-1): 10 ptiles x 2 query-tiles x 2 MFMA + med3 top-2 update ----
        if (s > 0) {
            int ss = s - 1;
            const unsigned char* cb = convb[ss & 1];
            const float* xb = xnhb[ss & 1];
            for (int t = 0; t < NPT; ++t) {
                h8 ahi = *(const h8*)(cb + t * TILE_B + lane * 16);   // lane-linear: conflict-free
                f4v xnh4 = *(const f4v*)(xb + t * 16 + quad * 4);     // C-init rows quad*4+r
                unsigned ic = 63u - (unsigned)(ss * NPT + t);         // wave-uniform tile code
#pragma unroll
                for (int j = 0; j < 2; ++j) {
                    f4v acc;
                    __builtin_amdgcn_s_setprio(1);
                    acc = __builtin_amdgcn_mfma_f32_16x16x32_f16(ahi, bhi[j], xnh4, 0, 0, 0);
                    acc = __builtin_amdgcn_mfma_f32_16x16x32_f16(ahi, blo[j], acc, 0, 0, 0);
                    __builtin_amdgcn_s_setprio(0);
#pragma unroll
                    for (int r = 0; r < 4; ++r) {
                        unsigned key = (__float_as_uint(acc[r]) & 0xFFFFFFC0u) | ic;  // v_and_or_b32
                        unsigned nb1;
                        asm("v_med3_u32 %0, %1, %2, %3"
                            : "=v"(nb1) : "v"(key), "v"(kb0[j][r]), "v"(kb1[j][r]));
                        kb0[j][r] = key > kb0[j][r] ? key : kb0[j][r];  // v_max_u32
                        kb1[j][r] = nb1;
                    }
                }
            }
        }
    }

    // epilogue: compute last super-tile
    __syncthreads();
    {
        int ss = NSUP - 1;
        const unsigned char* cb = convb[ss & 1];
        const float* xb = xnhb[ss & 1];
        for (int t = 0; t < NPT; ++t) {
            h8 ahi = *(const h8*)(cb + t * TILE_B + lane * 16);
            f4v xnh4 = *(const f4v*)(xb + t * 16 + quad * 4);
            unsigned ic = 63u - (unsigned)(ss * NPT + t);
#pragma unroll
            for (int j = 0; j < 2; ++j) {
                f4v acc;
                __builtin_amdgcn_s_setprio(1);
                acc = __builtin_amdgcn_mfma_f32_16x16x32_f16(ahi, bhi[j], xnh4, 0, 0, 0);
                acc = __builtin_amdgcn_mfma_f32_16x16x32_f16(ahi, blo[j], acc, 0, 0, 0);
                __builtin_amdgcn_s_setprio(0);
#pragma unroll
                for (int r = 0; r < 4; ++r) {
                    unsigned key = (__float_as_uint(acc[r]) & 0xFFFFFFC0u) | ic;
                    unsigned nb1;
                    asm("v_med3_u32 %0, %1, %2, %3"
                        : "=v"(nb1) : "v"(key), "v"(kb0[j][r]), "v"(kb1[j][r]));
                    kb0[j][r] = key > kb0[j][r] ? key : kb0[j][r];
                    kb1[j][r] = nb1;
                }
            }
        }
    }

    // decode + cross-quad merge (4 disjoint point subsets per query) -> block top-3
    // sort64 = (~(key|63) << 32) | gidx : ascending u64 == exact lex (quantized d, idx)
    int g = blockIdx.x;
    int qr4 = quad * 4;
#pragma unroll
    for (int j = 0; j < 2; ++j) {
        unsigned long long t0 = U64MAX, t1 = U64MAX, t2 = U64MAX;
#pragma unroll
        for (int r = 0; r < 4; ++r) {
#pragma unroll
            for (int h = 0; h < 2; ++h) {
                unsigned k = h ? kb1[j][r] : kb0[j][r];
                unsigned tile = 63u - (k & 63u);
                unsigned gi = (unsigned)(p0 + (int)tile * 16 + qr4 + r);
                unsigned long long e = ((unsigned long long)(~(k | 63u)) << 32) | gi;
                ins3u64(e, t0, t1, t2);
            }
        }
#pragma unroll
        for (int step = 16; step <= 32; step <<= 1) {
            unsigned long long o0 = shfl_xor_u64(t0, step);
            unsigned long long o1 = shfl_xor_u64(t1, step);
            unsigned long long o2 = shfl_xor_u64(t2, step);
            ins3u64(o0, t0, t1, t2);
            ins3u64(o1, t0, t1, t2);
            ins3u64(o2, t0, t1, t2);
        }
        if (quad == 0) {
            int qq = (w * 2 + j) * 16 + l15;
            size_t off = (size_t)qq * NC + (size_t)g * KNN;
            cand[off + 0] = t0; cand[off + 1] = t1; cand[off + 2] = t2;
        }
    }
}

// branchless compare-exchange (ascending)
#define CE(a, b) do { unsigned long long lo_ = (a) < (b) ? (a) : (b); \
                      unsigned long long hi_ = (a) < (b) ? (b) : (a); \
                      (a) = lo_; (b) = hi_; } while (0)

// ---------------- pass 2: parallel u64 top-8 merge -> exact f32 refine -> vote ----------------
__global__ __launch_bounds__(P2T) void k_pass2(const unsigned long long* __restrict__ cand,
                                               const float* __restrict__ train,
                                               const float* __restrict__ query,
                                               const unsigned* __restrict__ scale_u,
                                               const float* __restrict__ labels,
                                               float* __restrict__ out) {
    __shared__ unsigned long long smerge[64];   // 8 waves x top-8
    int q = blockIdx.x;
    int tid = threadIdx.x, lane = tid & 63, w = tid >> 6;
    const unsigned long long* cd = cand + (size_t)q * NC;

    // phase A: each thread owns <=3 candidates (1500 / 512); sort-3 (named regs, rule #20)
    unsigned long long c0 = cd[tid];
    unsigned long long c1 = cd[tid + P2T];
    unsigned long long c2 = (tid + 2 * P2T < NC) ? cd[tid + 2 * P2T] : U64MAX;
    CE(c0, c1); CE(c0, c2); CE(c1, c2);   // ascending

    // phase B: per-wave top-8 by repeated butterfly-u64-min extraction; lane 0 -> LDS
#pragma unroll
    for (int k = 0; k < 8; ++k) {
        unsigned long long m = c0;
#pragma unroll
        for (int st = 1; st < 64; st <<= 1) {
            unsigned long long o = shfl_xor_u64(m, st);
            if (o < m) m = o;
        }
        if (lane == 0) smerge[w * 8 + k] = m;
        bool win = (c0 == m);                 // exactly one lane (unique idx, m < U64MAX)
        c0 = win ? c1 : c0;
        c1 = win ? c2 : c1;
        c2 = win ? U64MAX : c2;
    }
    __syncthreads();
    if (w != 0) return;

    // phase C (wave 0): merge 8x8 wave winners -> global top-8; lane k keeps idx of rank k
    int myi = 0x7fffffff;
    {
        unsigned long long cur = smerge[lane];   // 64 real, unique entries
#pragma unroll
        for (int k = 0; k < 8; ++k) {
            unsigned long long m = cur;
#pragma unroll
            for (int st = 1; st < 64; st <<= 1) {
                unsigned long long o = shfl_xor_u64(m, st);
                if (o < m) m = o;
            }
            if (lane == k) myi = (int)(unsigned)m;
            if (cur == m) cur = U64MAX;
        }
    }

    // exact f32 scaled query + qn (same op order as the verified path)
    float inv[DIMS], qs_[DIMS], qn_ = 0.f;
#pragma unroll
    for (int d = 0; d < DIMS; ++d) {
        float sc = __uint_as_float(scale_u[d]);
        float iv = (sc != 0.f) ? 1.f / sc : 0.f;
        float v = query[(size_t)q * DIMS + d] * iv;
        inv[d] = iv; qs_[d] = v;
        qn_ = fmaf(v, v, qn_);
    }

    float myd2 = 3.4e38f;
    if (lane < 8) {
        const float* r = train + (size_t)myi * DIMS;
        float xnv = 0.f, dot = 0.f;
#pragma unroll
        for (int d = 0; d < DIMS; ++d) {
            float v = r[d] * inv[d];
            xnv = fmaf(v, v, xnv);
            dot = fmaf(qs_[d], v, dot);
        }
        myd2 = fmaf(-2.f, dot, qn_ + xnv);
    }

    float bd[KNN] = {3.4e38f, 3.4e38f, 3.4e38f};
    int   bi[KNN] = {0x7fffffff, 0x7fffffff, 0x7fffffff};
#pragma unroll
    for (int k = 0; k < 8; ++k) {
        float dk = __shfl(myd2, k, 64);
        int   ik = __shfl(myi, k, 64);
        insert3(dk, ik, bd, bi);
    }

    if (lane == 0) {
        float kd[KNN];
#pragma unroll
        for (int k = 0; k < KNN; ++k) kd[k] = sqrtf(fmaxf(bd[k], 0.f));
        float lab[KNN][NCLS];
#pragma unroll
        for (int k = 0; k < KNN; ++k) {
            const float* lr = labels + (size_t)bi[k] * NCLS;
#pragma unroll
            for (int c = 0; c < NCLS; ++c) lab[k][c] = lr[c];
        }
        float votes[NCLS];
#pragma unroll
        for (int c = 0; c < NCLS; ++c) votes[c] = 0.f;
#pragma unroll
        for (int k = 0; k < KNN; ++k) {
            float ks = (kd[k] == 0.f) ? 1.f : kd[k];
#pragma unroll
            for (int c = 0; c < NCLS; ++c) votes[c] += lab[k][c] / ks;
        }
        int best = 0; float bv = votes[0];
#pragma unroll
        for (int c = 1; c < NCLS; ++c) { if (votes[c] > bv) { bv = votes[c]; best = c; } }
        bool zero_hit = (kd[0] == 0.f);
#pragma unroll
        for (int k = 0; k < KNN; ++k) out[(size_t)q * KNN + k] = kd[k];
        float* ro = out + (size_t)BQ * KNN + (size_t)q * NCLS;
#pragma unroll
        for (int c = 0; c < NCLS; ++c)
            ro[c] = zero_hit ? lab[0][c] : ((c == best) ? 1.f : 0.f);
    }
}

extern "C" void kernel_launch(void* const* d_in, const int* in_sizes, int n_in,
                              void* d_out, int out_size, void* d_ws, size_t ws_size,
                              hipStream_t stream) {
    const float* query  = (const float*)d_in[0];
    const float* train  = (const float*)d_in[1];
    const float* labels = (const float*)d_in[2];
    float* out = (float*)d_out;

    // ws layout:
    //   [0)       scale_u: 32 u32 (128 B)
    //   [128)     Qhi: 512*32 f16 (32768 B)
    //   [32896)   Qlo: 512*32 f16 (32768 B)
    //   [65664)   cand: 512*1500 u64 (6144000 B)   total ~6.2 MB
    char* ws = (char*)d_ws;
    unsigned*  scale_u = (unsigned*)ws;
    _Float16*  Qhi = (_Float16*)(ws + 128);
    _Float16*  Qlo = (_Float16*)(ws + 32896);
    unsigned long long* cand = (unsigned long long*)(ws + 65664);

    hipMemsetAsync(ws, 0, 128, stream);  // zero scale accumulators
    k_scale<<<SCB, 256, 0, stream>>>(train, scale_u);
    k_qprep<<<8, 64, 0, stream>>>(query, scale_u, Qhi, Qlo);
    k_pass1<<<NB, P1T, 0, stream>>>(train, scale_u, Qhi, Qlo, cand);
    k_pass2<<<BQ, P2T, 0, stream>>>(cand, train, query, scale_u, labels, out);
}

// Round 16
// 161.172 us; speedup vs baseline: 3.3250x; 1.0221x over previous
//
#include <hip/hip_runtime.h>
#include <math.h>

typedef _Float16 h8 __attribute__((ext_vector_type(8)));
typedef float    f4v __attribute__((ext_vector_type(4)));

#define N_TRAIN 400000
#define DIMS    27
#define BQ      512
#define NCLS    11
#define KNN     3
#define NB      500            // pass-1 blocks
#define P1T     1024           // pass-1 threads (16 waves)
#define PTS_BLK 800            // points per block (500*800 = 400000 exact)
#define PTS_SUP 160            // points per super-tile
#define NSUP    5
#define NPT     10
#define RAWF    4320           // floats per super-tile (160*27)
#define TILE_B  1024           // conv bytes per ptile (hi fragments only)
#define NC      (NB * KNN)     // candidates per query (1500)
#define SCB     391            // k_scale blocks (391*256 = 100096 >= 100000 groups of 4 rows)
#define P2T     512            // pass-2 threads (8 waves)

#define U64MAX 0xFFFFFFFFFFFFFFFFULL

// ---------------- scale = max(|train|, axis=0) — register-resident, no LDS staging ----------------
// (R6-verified kernel.)
__global__ __launch_bounds__(256) void k_scale(const float* __restrict__ train,
                                               unsigned* __restrict__ scale_u) {
    __shared__ float red[4][DIMS];
    int tid = threadIdx.x;
    int lane = tid & 63, w = tid >> 6;
    int g = blockIdx.x * 256 + tid;            // 4-row group id
    float m[DIMS];
#pragma unroll
    for (int d = 0; d < DIMS; ++d) m[d] = 0.f;
    if (g < N_TRAIN / 4) {
        const uint4* p = (const uint4*)(train + (size_t)g * (4 * DIMS));
#pragma unroll
        for (int k = 0; k < DIMS; ++k) {
            uint4 v = p[k];
            m[(4 * k + 0) % DIMS] = fmaxf(m[(4 * k + 0) % DIMS], fabsf(__uint_as_float(v.x)));
            m[(4 * k + 1) % DIMS] = fmaxf(m[(4 * k + 1) % DIMS], fabsf(__uint_as_float(v.y)));
            m[(4 * k + 2) % DIMS] = fmaxf(m[(4 * k + 2) % DIMS], fabsf(__uint_as_float(v.z)));
            m[(4 * k + 3) % DIMS] = fmaxf(m[(4 * k + 3) % DIMS], fabsf(__uint_as_float(v.w)));
        }
    }
#pragma unroll
    for (int d = 0; d < DIMS; ++d) {           // wave butterfly (27 dims x 6 steps)
        float t = m[d];
#pragma unroll
        for (int st = 1; st < 64; st <<= 1) t = fmaxf(t, __shfl_xor(t, st, 64));
        m[d] = t;
    }
    if (lane == 0) {
#pragma unroll
        for (int d = 0; d < DIMS; ++d) red[w][d] = m[d];
    }
    __syncthreads();
    if (tid < DIMS) {
        float v = fmaxf(fmaxf(red[0][tid], red[1][tid]), fmaxf(red[2][tid], red[3][tid]));
        atomicMax(&scale_u[tid], __float_as_uint(v)); // values >= 0: uint order == float order
    }
}

// ---------------- query prep: f16 B-fragments (hi only; lo MFMA dropped in pass1) ----------------
__global__ __launch_bounds__(64) void k_qprep(const float* __restrict__ query,
                                              const unsigned* __restrict__ scale_u,
                                              _Float16* __restrict__ Qhi) {
    int q = blockIdx.x * 64 + threadIdx.x;
    if (q >= BQ) return;
    const float* r = query + (size_t)q * DIMS;
#pragma unroll
    for (int d = 0; d < 32; ++d) {
        _Float16 hi = (_Float16)0.f;
        if (d < DIMS) {
            float sc = __uint_as_float(scale_u[d]);
            float inv = (sc != 0.f) ? 1.f / sc : 0.f;   // divide_no_nan
            hi = (_Float16)(r[d] * inv);
        }
        // d>=27: 0 (A slots 27..31 are 0; xn folded via f32 C-init)
        Qhi[q * 32 + d] = hi;
    }
}

// lexicographic (key, idx) insert into ascending sorted triple — matches top_k ties
__device__ __forceinline__ void insert3(float d, int i, float* bd, int* bi) {
    if (d < bd[2] || (d == bd[2] && i < bi[2])) {
        if (d < bd[1] || (d == bd[1] && i < bi[1])) {
            bd[2] = bd[1]; bi[2] = bi[1];
            if (d < bd[0] || (d == bd[0] && i < bi[0])) {
                bd[1] = bd[0]; bi[1] = bi[0];
                bd[0] = d; bi[0] = i;
            } else { bd[1] = d; bi[1] = i; }
        } else { bd[2] = d; bi[2] = i; }
    }
}

// 64-bit xor-shuffle via two 32-bit shuffles
__device__ __forceinline__ unsigned long long shfl_xor_u64(unsigned long long v, int m) {
    unsigned lo = (unsigned)v, hi = (unsigned)(v >> 32);
    lo = __shfl_xor(lo, m, 64);
    hi = __shfl_xor(hi, m, 64);
    return ((unsigned long long)hi << 32) | lo;
}

// branchless insert into ascending sorted-3 of u64 (keep 3 smallest)
__device__ __forceinline__ void ins3u64(unsigned long long e,
                                        unsigned long long& t0,
                                        unsigned long long& t1,
                                        unsigned long long& t2) {
    unsigned long long a  = e < t2 ? e : t2;     // candidate enters bottom slot
    unsigned long long n2 = t1 > a ? t1 : a;
    unsigned long long n1 = t1 < a ? t1 : a;
    t2 = n2;
    unsigned long long m1 = t0 > n1 ? t0 : n1;
    t0 = t0 < n1 ? t0 : n1;
    t1 = m1;
}

__device__ __forceinline__ void stage16(const float* g, float* l) {
    __builtin_amdgcn_global_load_lds((const __attribute__((address_space(1))) void*)g,
                                     (__attribute__((address_space(3))) void*)l, 16, 0, 0);
}

// ---------------- pass 1: single-MFMA f16 scan + exact-f32 xn via C-init ----------------
// R16 numerics: dot approx = ah·bh only (both lo terms dropped; total error ~1e-2 worst on d^2,
// vs the ~0.1 interloper margin of the exact-f32 top-8 refine in pass2). xn exact via f32 C-init
// (xnh[p] = 64 - xn/2, includes +64 uint-order bias). Per (j,tile): 1 MFMA + 12 tracker ops.
// Conv-write bank conflict fixed by XOR swizzle: write slot (p&15)^(gq<<2), read slot
// l15^(quad<<2) — both lane-constant, hoisted (4-way -> 2-way=free conflicts).
// LDS 56.5 KB -> 2 blocks/CU. Tracker/decode/pass2 = R14/R15-verified.
__global__ __attribute__((amdgpu_flat_work_group_size(P1T, P1T)))
__attribute__((amdgpu_waves_per_eu(4)))
void k_pass1(const float* __restrict__ train,
             const unsigned* __restrict__ scale_u,
             const _Float16* __restrict__ Qhi,
             unsigned long long* __restrict__ cand) {
    __shared__ float s_inv[32];
    __shared__ __align__(16) float raw[2][RAWF];                     // 34560 B
    __shared__ __align__(16) unsigned char convb[2][NPT * TILE_B];   // 20480 B
    __shared__ __align__(16) float xnhb[2][NPT * 16];                // 1280 B (xn C-init per point)

    int tid = threadIdx.x;
    if (tid < 32) {
        float sc = __uint_as_float(scale_u[tid]);       // 0 for d>=27 (memset)
        s_inv[tid] = (sc != 0.f) ? 1.f / sc : 0.f;
    }
    int lane = tid & 63, w = tid >> 6;                  // w in [0,16)
    int l15 = lane & 15, quad = lane >> 4;
    int rdoff = quad * 256 + ((l15 ^ (quad << 2)) * 16);   // swizzled A-frag read offset (hoisted)

    h8 bhi[2];
#pragma unroll
    for (int j = 0; j < 2; ++j) {
        int qt = w * 2 + j;                             // query tile 0..31
        size_t e = (size_t)(qt * 16 + l15) * 32 + quad * 8;
        bhi[j] = *(const h8*)(Qhi + e);
    }

    // top-2 keys per (query-tile j, acc row r); 0 = -inf sentinel (real keys ~0x41BC.. +)
    unsigned kb0[2][4], kb1[2][4];
#pragma unroll
    for (int j = 0; j < 2; ++j)
#pragma unroll
        for (int r = 0; r < 4; ++r) { kb0[j][r] = 0u; kb1[j][r] = 0u; }

    int p0 = blockIdx.x * PTS_BLK;
    const float* gsup = train + (size_t)p0 * DIMS;   // 16B aligned (800*108 % 16 == 0)

    // async stage super-tile 0 (1024 threads: 4096 floats + 224 tail)
    {
        const float* gp = gsup; float* lp = raw[0];
        stage16(gp + tid * 4, lp + tid * 4);
        if (tid < 56) stage16(gp + 4096 + tid * 4, lp + 4096 + tid * 4);
    }

    for (int s = 0; s < NSUP; ++s) {
        __syncthreads();   // drains stage(s) vmcnt; raw[s&1] ready; convb[s&1] free (compute(s-2) done)

        if (s + 1 < NSUP) {   // async stage next super-tile; drains at next barrier
            const float* gp = gsup + (size_t)(s + 1) * RAWF;
            float* lp = raw[(s + 1) & 1];
            stage16(gp + tid * 4, lp + tid * 4);
            if (tid < 56) stage16(gp + 4096 + tid * 4, lp + 4096 + tid * 4);
        }

        // ---- conv(s): task = (point p, kblock gq of 8 dims); 640 tasks, waves 10..15 skip ----
        const float* rw = raw[s & 1];
        if (tid < PTS_SUP * 4) {
            int p = tid >> 2, gq = tid & 3;
            float x[8]; float part = 0.f;
#pragma unroll
            for (int i = 0; i < 8; ++i) {
                int d = gq * 8 + i;
                int dc = d < DIMS ? d : (DIMS - 1);     // clamp; s_inv[d>=27]=0 zeroes value
                float v = rw[p * DIMS + dc] * s_inv[d];
                x[i] = v;
                part = fmaf(v, v, part);
            }
            part += __shfl_xor(part, 1, 64);
            part += __shfl_xor(part, 2, 64);            // all 4 kblock-lanes hold xn
            h8 hv;
#pragma unroll
            for (int i = 0; i < 8; ++i) hv[i] = (_Float16)x[i];
            if (gq == 3)                                // one lane per point: exact f32 xn + bias
                xnhb[s & 1][p] = fmaf(-0.5f, part, 64.f);
            // XOR-swizzled write slot: (p&15)^(gq<<2) (4-way bank conflict -> free 2-way)
            unsigned char* dstb = convb[s & 1] + (p >> 4) * TILE_B + gq * 256
                                  + (((p & 15) ^ (gq << 2)) * 16);
            *(h8*)dstb = hv;
        }

        // ---- compute(s-1): 10 ptiles x 2 query-tiles x 1 MFMA + med3 top-2 update ----
        if (s > 0) {
            int ss = s - 1;
            const unsigned char* cb = convb[ss & 1];
            const float* xb = xnhb[ss & 1];
            for (int t = 0; t < NPT; ++t) {
                h8 ahi = *(const h8*)(cb + t * TILE_B + rdoff);       // swizzled, conflict-free
                f4v xnh4 = *(const f4v*)(xb + t * 16 + quad * 4);     // C-init rows quad*4+r
                unsigned ic = 63u - (unsigned)(ss * NPT + t);         // wave-uniform tile code
#pragma unroll
                for (int j = 0; j < 2; ++j) {
                    f4v acc;
                    __builtin_amdgcn_s_setprio(1);
                    acc = __builtin_amdgcn_mfma_f32_16x16x32_f16(ahi, bhi[j], xnh4, 0, 0, 0);
                    __builtin_amdgcn_s_setprio(0);
#pragma unroll
                    for (int r = 0; r < 4; ++r) {
                        unsigned key = (__float_as_uint(acc[r]) & 0xFFFFFFC0u) | ic;  // v_and_or_b32
                        unsigned nb1;
                        asm("v_med3_u32 %0, %1, %2, %3"
                            : "=v"(nb1) : "v"(key), "v"(kb0[j][r]), "v"(kb1[j][r]));
                        kb0[j][r] = key > kb0[j][r] ? key : kb0[j][r];  // v_max_u32
                        kb1[j][r] = nb1;
                    }
                }
            }
        }
    }

    // epilogue: compute last super-tile
    __syncthreads();
    {
        int ss = NSUP - 1;
        const unsigned char* cb = convb[ss & 1];
        const float* xb = xnhb[ss & 1];
        for (int t = 0; t < NPT; ++t) {
            h8 ahi = *(const h8*)(cb + t * TILE_B + rdoff);
            f4v xnh4 = *(const f4v*)(xb + t * 16 + quad * 4);
            unsigned ic = 63u - (unsigned)(ss * NPT + t);
#pragma unroll
            for (int j = 0; j < 2; ++j) {
                f4v acc;
                __builtin_amdgcn_s_setprio(1);
                acc = __builtin_amdgcn_mfma_f32_16x16x32_f16(ahi, bhi[j], xnh4, 0, 0, 0);
                __builtin_amdgcn_s_setprio(0);
#pragma unroll
                for (int r = 0; r < 4; ++r) {
                    unsigned key = (__float_as_uint(acc[r]) & 0xFFFFFFC0u) | ic;
                    unsigned nb1;
                    asm("v_med3_u32 %0, %1, %2, %3"
                        : "=v"(nb1) : "v"(key), "v"(kb0[j][r]), "v"(kb1[j][r]));
                    kb0[j][r] = key > kb0[j][r] ? key : kb0[j][r];
                    kb1[j][r] = nb1;
                }
            }
        }
    }

    // decode + cross-quad merge (4 disjoint point subsets per query) -> block top-3
    // sort64 = (~(key|63) << 32) | gidx : ascending u64 == exact lex (quantized d, idx)
    // NOTE: swizzle affects only LDS placement; tracker keys/indices unchanged (r maps to
    // point quad*4+r via the xnh4/C-row pairing, same as R15).
    int g = blockIdx.x;
    int qr4 = quad * 4;
#pragma unroll
    for (int j = 0; j < 2; ++j) {
        unsigned long long t0 = U64MAX, t1 = U64MAX, t2 = U64MAX;
#pragma unroll
        for (int r = 0; r < 4; ++r) {
#pragma unroll
            for (int h = 0; h < 2; ++h) {
                unsigned k = h ? kb1[j][r] : kb0[j][r];
                unsigned tile = 63u - (k & 63u);
                unsigned gi = (unsigned)(p0 + (int)tile * 16 + qr4 + r);
                unsigned long long e = ((unsigned long long)(~(k | 63u)) << 32) | gi;
                ins3u64(e, t0, t1, t2);
            }
        }
#pragma unroll
        for (int step = 16; step <= 32; step <<= 1) {
            unsigned long long o0 = shfl_xor_u64(t0, step);
            unsigned long long o1 = shfl_xor_u64(t1, step);
            unsigned long long o2 = shfl_xor_u64(t2, step);
            ins3u64(o0, t0, t1, t2);
            ins3u64(o1, t0, t1, t2);
            ins3u64(o2, t0, t1, t2);
        }
        if (quad == 0) {
            int qq = (w * 2 + j) * 16 + l15;
            size_t off = (size_t)qq * NC + (size_t)g * KNN;
            cand[off + 0] = t0; cand[off + 1] = t1; cand[off + 2] = t2;
        }
    }
}

// branchless compare-exchange (ascending)
#define CE(a, b) do { unsigned long long lo_ = (a) < (b) ? (a) : (b); \
                      unsigned long long hi_ = (a) < (b) ? (b) : (a); \
                      (a) = lo_; (b) = hi_; } while (0)

// ---------------- pass 2: parallel u64 top-8 merge -> exact f32 refine -> vote ----------------
__global__ __launch_bounds__(P2T) void k_pass2(const unsigned long long* __restrict__ cand,
                                               const float* __restrict__ train,
                                               const float* __restrict__ query,
                                               const unsigned* __restrict__ scale_u,
                                               const float* __restrict__ labels,
                                               float* __restrict__ out) {
    __shared__ unsigned long long smerge[64];   // 8 waves x top-8
    int q = blockIdx.x;
    int tid = threadIdx.x, lane = tid & 63, w = tid >> 6;
    const unsigned long long* cd = cand + (size_t)q * NC;

    // phase A: each thread owns <=3 candidates (1500 / 512); sort-3 (named regs, rule #20)
    unsigned long long c0 = cd[tid];
    unsigned long long c1 = cd[tid + P2T];
    unsigned long long c2 = (tid + 2 * P2T < NC) ? cd[tid + 2 * P2T] : U64MAX;
    CE(c0, c1); CE(c0, c2); CE(c1, c2);   // ascending

    // phase B: per-wave top-8 by repeated butterfly-u64-min extraction; lane 0 -> LDS
#pragma unroll
    for (int k = 0; k < 8; ++k) {
        unsigned long long m = c0;
#pragma unroll
        for (int st = 1; st < 64; st <<= 1) {
            unsigned long long o = shfl_xor_u64(m, st);
            if (o < m) m = o;
        }
        if (lane == 0) smerge[w * 8 + k] = m;
        bool win = (c0 == m);                 // exactly one lane (unique idx, m < U64MAX)
        c0 = win ? c1 : c0;
        c1 = win ? c2 : c1;
        c2 = win ? U64MAX : c2;
    }
    __syncthreads();
    if (w != 0) return;

    // phase C (wave 0): merge 8x8 wave winners -> global top-8; lane k keeps idx of rank k
    int myi = 0x7fffffff;
    {
        unsigned long long cur = smerge[lane];   // 64 real, unique entries
#pragma unroll
        for (int k = 0; k < 8; ++k) {
            unsigned long long m = cur;
#pragma unroll
            for (int st = 1; st < 64; st <<= 1) {
                unsigned long long o = shfl_xor_u64(m, st);
                if (o < m) m = o;
            }
            if (lane == k) myi = (int)(unsigned)m;
            if (cur == m) cur = U64MAX;
        }
    }

    // exact f32 scaled query + qn (same op order as the verified path)
    float inv[DIMS], qs_[DIMS], qn_ = 0.f;
#pragma unroll
    for (int d = 0; d < DIMS; ++d) {
        float sc = __uint_as_float(scale_u[d]);
        float iv = (sc != 0.f) ? 1.f / sc : 0.f;
        float v = query[(size_t)q * DIMS + d] * iv;
        inv[d] = iv; qs_[d] = v;
        qn_ = fmaf(v, v, qn_);
    }

    float myd2 = 3.4e38f;
    if (lane < 8) {
        const float* r = train + (size_t)myi * DIMS;
        float xnv = 0.f, dot = 0.f;
#pragma unroll
        for (int d = 0; d < DIMS; ++d) {
            float v = r[d] * inv[d];
            xnv = fmaf(v, v, xnv);
            dot = fmaf(qs_[d], v, dot);
        }
        myd2 = fmaf(-2.f, dot, qn_ + xnv);
    }

    float bd[KNN] = {3.4e38f, 3.4e38f, 3.4e38f};
    int   bi[KNN] = {0x7fffffff, 0x7fffffff, 0x7fffffff};
#pragma unroll
    for (int k = 0; k < 8; ++k) {
        float dk = __shfl(myd2, k, 64);
        int   ik = __shfl(myi, k, 64);
        insert3(dk, ik, bd, bi);
    }

    if (lane == 0) {
        float kd[KNN];
#pragma unroll
        for (int k = 0; k < KNN; ++k) kd[k] = sqrtf(fmaxf(bd[k], 0.f));
        float lab[KNN][NCLS];
#pragma unroll
        for (int k = 0; k < KNN; ++k) {
            const float* lr = labels + (size_t)bi[k] * NCLS;
#pragma unroll
            for (int c = 0; c < NCLS; ++c) lab[k][c] = lr[c];
        }
        float votes[NCLS];
#pragma unroll
        for (int c = 0; c < NCLS; ++c) votes[c] = 0.f;
#pragma unroll
        for (int k = 0; k < KNN; ++k) {
            float ks = (kd[k] == 0.f) ? 1.f : kd[k];
#pragma unroll
            for (int c = 0; c < NCLS; ++c) votes[c] += lab[k][c] / ks;
        }
        int best = 0; float bv = votes[0];
#pragma unroll
        for (int c = 1; c < NCLS; ++c) { if (votes[c] > bv) { bv = votes[c]; best = c; } }
        bool zero_hit = (kd[0] == 0.f);
#pragma unroll
        for (int k = 0; k < KNN; ++k) out[(size_t)q * KNN + k] = kd[k];
        float* ro = out + (size_t)BQ * KNN + (size_t)q * NCLS;
#pragma unroll
        for (int c = 0; c < NCLS; ++c)
            ro[c] = zero_hit ? lab[0][c] : ((c == best) ? 1.f : 0.f);
    }
}

extern "C" void kernel_launch(void* const* d_in, const int* in_sizes, int n_in,
                              void* d_out, int out_size, void* d_ws, size_t ws_size,
                              hipStream_t stream) {
    const float* query  = (const float*)d_in[0];
    const float* train  = (const float*)d_in[1];
    const float* labels = (const float*)d_in[2];
    float* out = (float*)d_out;

    // ws layout:
    //   [0)       scale_u: 32 u32 (128 B)
    //   [128)     Qhi: 512*32 f16 (32768 B)
    //   [32896)   cand: 512*1500 u64 (6144000 B)   total ~6.2 MB
    char* ws = (char*)d_ws;
    unsigned*  scale_u = (unsigned*)ws;
    _Float16*  Qhi = (_Float16*)(ws + 128);
    unsigned long long* cand = (unsigned long long*)(ws + 32896);

    hipMemsetAsync(ws, 0, 128, stream);  // zero scale accumulators
    k_scale<<<SCB, 256, 0, stream>>>(train, scale_u);
    k_qprep<<<8, 64, 0, stream>>>(query, scale_u, Qhi);
    k_pass1<<<NB, P1T, 0, stream>>>(train, scale_u, Qhi, cand);
    k_pass2<<<BQ, P2T, 0, stream>>>(cand, train, query, scale_u, labels, out);
}

// Round 17
// 159.321 us; speedup vs baseline: 3.3636x; 1.0116x over previous
//
#include <hip/hip_runtime.h>
#include <math.h>

typedef _Float16 h8 __attribute__((ext_vector_type(8)));
typedef float    f4v __attribute__((ext_vector_type(4)));

#define N_TRAIN 400000
#define DIMS    27
#define BQ      512
#define NCLS    11
#define KNN     3
#define NB      500            // pass-1 blocks
#define P1T     1024           // pass-1 threads (16 waves)
#define PTS_BLK 800            // points per block (500*800 = 400000 exact)
#define PTS_SUP 160            // points per super-tile
#define NSUP    5
#define NPT     10
#define RAWF    4320           // floats per super-tile (160*27)
#define TILE_B  1024           // conv bytes per ptile (hi fragments only)
#define NC      (NB * KNN)     // candidates per query (1500)
#define SCB     391            // k_scale blocks (391*256 = 100096 >= 100000 groups of 4 rows)
#define P2T     512            // pass-2 threads (8 waves)

#define U64MAX 0xFFFFFFFFFFFFFFFFULL

// ---------------- scale = max(|train|, axis=0) — register-resident, no LDS staging ----------------
// (R6-verified kernel.)
__global__ __launch_bounds__(256) void k_scale(const float* __restrict__ train,
                                               unsigned* __restrict__ scale_u) {
    __shared__ float red[4][DIMS];
    int tid = threadIdx.x;
    int lane = tid & 63, w = tid >> 6;
    int g = blockIdx.x * 256 + tid;            // 4-row group id
    float m[DIMS];
#pragma unroll
    for (int d = 0; d < DIMS; ++d) m[d] = 0.f;
    if (g < N_TRAIN / 4) {
        const uint4* p = (const uint4*)(train + (size_t)g * (4 * DIMS));
#pragma unroll
        for (int k = 0; k < DIMS; ++k) {
            uint4 v = p[k];
            m[(4 * k + 0) % DIMS] = fmaxf(m[(4 * k + 0) % DIMS], fabsf(__uint_as_float(v.x)));
            m[(4 * k + 1) % DIMS] = fmaxf(m[(4 * k + 1) % DIMS], fabsf(__uint_as_float(v.y)));
            m[(4 * k + 2) % DIMS] = fmaxf(m[(4 * k + 2) % DIMS], fabsf(__uint_as_float(v.z)));
            m[(4 * k + 3) % DIMS] = fmaxf(m[(4 * k + 3) % DIMS], fabsf(__uint_as_float(v.w)));
        }
    }
#pragma unroll
    for (int d = 0; d < DIMS; ++d) {           // wave butterfly (27 dims x 6 steps)
        float t = m[d];
#pragma unroll
        for (int st = 1; st < 64; st <<= 1) t = fmaxf(t, __shfl_xor(t, st, 64));
        m[d] = t;
    }
    if (lane == 0) {
#pragma unroll
        for (int d = 0; d < DIMS; ++d) red[w][d] = m[d];
    }
    __syncthreads();
    if (tid < DIMS) {
        float v = fmaxf(fmaxf(red[0][tid], red[1][tid]), fmaxf(red[2][tid], red[3][tid]));
        atomicMax(&scale_u[tid], __float_as_uint(v)); // values >= 0: uint order == float order
    }
}

// ---------------- query prep: f16 B-fragments (hi only) ----------------
__global__ __launch_bounds__(64) void k_qprep(const float* __restrict__ query,
                                              const unsigned* __restrict__ scale_u,
                                              _Float16* __restrict__ Qhi) {
    int q = blockIdx.x * 64 + threadIdx.x;
    if (q >= BQ) return;
    const float* r = query + (size_t)q * DIMS;
#pragma unroll
    for (int d = 0; d < 32; ++d) {
        _Float16 hi = (_Float16)0.f;
        if (d < DIMS) {
            float sc = __uint_as_float(scale_u[d]);
            float inv = (sc != 0.f) ? 1.f / sc : 0.f;   // divide_no_nan
            hi = (_Float16)(r[d] * inv);
        }
        // d>=27: 0 (A slots 27..31 are 0; xn folded via f32 C-init)
        Qhi[q * 32 + d] = hi;
    }
}

// lexicographic (key, idx) insert into ascending sorted triple — matches top_k ties
__device__ __forceinline__ void insert3(float d, int i, float* bd, int* bi) {
    if (d < bd[2] || (d == bd[2] && i < bi[2])) {
        if (d < bd[1] || (d == bd[1] && i < bi[1])) {
            bd[2] = bd[1]; bi[2] = bi[1];
            if (d < bd[0] || (d == bd[0] && i < bi[0])) {
                bd[1] = bd[0]; bi[1] = bi[0];
                bd[0] = d; bi[0] = i;
            } else { bd[1] = d; bi[1] = i; }
        } else { bd[2] = d; bi[2] = i; }
    }
}

// 64-bit xor-shuffle via two 32-bit shuffles
__device__ __forceinline__ unsigned long long shfl_xor_u64(unsigned long long v, int m) {
    unsigned lo = (unsigned)v, hi = (unsigned)(v >> 32);
    lo = __shfl_xor(lo, m, 64);
    hi = __shfl_xor(hi, m, 64);
    return ((unsigned long long)hi << 32) | lo;
}

// branchless insert into ascending sorted-3 of u64 (keep 3 smallest)
__device__ __forceinline__ void ins3u64(unsigned long long e,
                                        unsigned long long& t0,
                                        unsigned long long& t1,
                                        unsigned long long& t2) {
    unsigned long long a  = e < t2 ? e : t2;     // candidate enters bottom slot
    unsigned long long n2 = t1 > a ? t1 : a;
    unsigned long long n1 = t1 < a ? t1 : a;
    t2 = n2;
    unsigned long long m1 = t0 > n1 ? t0 : n1;
    t0 = t0 < n1 ? t0 : n1;
    t1 = m1;
}

__device__ __forceinline__ void stage16(const float* g, float* l) {
    __builtin_amdgcn_global_load_lds((const __attribute__((address_space(1))) void*)g,
                                     (__attribute__((address_space(3))) void*)l, 16, 0, 0);
}

// tracker: exact top-2 insert via med3 (invariant kb0 >= kb1); 3 VALU ops/elem
#define TRK(ACCR, IC, B0, B1) do { \
    unsigned key_ = (__float_as_uint(ACCR) & 0xFFFFFFC0u) | (IC); \
    unsigned nb1_; \
    asm("v_med3_u32 %0, %1, %2, %3" : "=v"(nb1_) : "v"(key_), "v"(B0), "v"(B1)); \
    B0 = key_ > (B0) ? key_ : (B0); \
    B1 = nb1_; \
} while (0)

// ---------------- pass 1: single-MFMA f16 scan + exact-f32 xn via C-init ----------------
// (R16-verified numerics: dot = ah·bh; xn exact via f32 C-init with +64 bias; med3 top-2
// trackers; pass2 exact-f32 refine absorbs the f16 error.)
// R17: compute loop restructured for issue efficiency — per-super-tile hoisted LDS bases,
// FULL unroll of the t-loop (ds_read offsets become immediates; deep lgkmcnt pipelining),
// setprio raised once per super-tile instead of per tile. Computation bit-identical to R16.
__global__ __attribute__((amdgpu_flat_work_group_size(P1T, P1T)))
__attribute__((amdgpu_waves_per_eu(4)))
void k_pass1(const float* __restrict__ train,
             const unsigned* __restrict__ scale_u,
             const _Float16* __restrict__ Qhi,
             unsigned long long* __restrict__ cand) {
    __shared__ float s_inv[32];
    __shared__ __align__(16) float raw[2][RAWF];                     // 34560 B
    __shared__ __align__(16) unsigned char convb[2][NPT * TILE_B];   // 20480 B
    __shared__ __align__(16) float xnhb[2][NPT * 16];                // 1280 B (xn C-init per point)

    int tid = threadIdx.x;
    if (tid < 32) {
        float sc = __uint_as_float(scale_u[tid]);       // 0 for d>=27 (memset)
        s_inv[tid] = (sc != 0.f) ? 1.f / sc : 0.f;
    }
    int lane = tid & 63, w = tid >> 6;                  // w in [0,16)
    int l15 = lane & 15, quad = lane >> 4;
    int rdoff = quad * 256 + ((l15 ^ (quad << 2)) * 16);   // swizzled A-frag read offset (hoisted)

    h8 bhi[2];
#pragma unroll
    for (int j = 0; j < 2; ++j) {
        int qt = w * 2 + j;                             // query tile 0..31
        size_t e = (size_t)(qt * 16 + l15) * 32 + quad * 8;
        bhi[j] = *(const h8*)(Qhi + e);
    }

    // top-2 keys per (query-tile j, acc row r); 0 = -inf sentinel (real keys ~0x41BC.. +)
    unsigned kb0[2][4], kb1[2][4];
#pragma unroll
    for (int j = 0; j < 2; ++j)
#pragma unroll
        for (int r = 0; r < 4; ++r) { kb0[j][r] = 0u; kb1[j][r] = 0u; }

    int p0 = blockIdx.x * PTS_BLK;
    const float* gsup = train + (size_t)p0 * DIMS;   // 16B aligned (800*108 % 16 == 0)

    // async stage super-tile 0 (1024 threads: 4096 floats + 224 tail)
    {
        const float* gp = gsup; float* lp = raw[0];
        stage16(gp + tid * 4, lp + tid * 4);
        if (tid < 56) stage16(gp + 4096 + tid * 4, lp + 4096 + tid * 4);
    }

    for (int s = 0; s < NSUP; ++s) {
        __syncthreads();   // drains stage(s) vmcnt; raw[s&1] ready; convb[s&1] free (compute(s-2) done)

        if (s + 1 < NSUP) {   // async stage next super-tile; drains at next barrier
            const float* gp = gsup + (size_t)(s + 1) * RAWF;
            float* lp = raw[(s + 1) & 1];
            stage16(gp + tid * 4, lp + tid * 4);
            if (tid < 56) stage16(gp + 4096 + tid * 4, lp + 4096 + tid * 4);
        }

        // ---- conv(s): task = (point p, kblock gq of 8 dims); 640 tasks, waves 10..15 skip ----
        const float* rw = raw[s & 1];
        if (tid < PTS_SUP * 4) {
            int p = tid >> 2, gq = tid & 3;
            float x[8]; float part = 0.f;
#pragma unroll
            for (int i = 0; i < 8; ++i) {
                int d = gq * 8 + i;
                int dc = d < DIMS ? d : (DIMS - 1);     // clamp; s_inv[d>=27]=0 zeroes value
                float v = rw[p * DIMS + dc] * s_inv[d];
                x[i] = v;
                part = fmaf(v, v, part);
            }
            part += __shfl_xor(part, 1, 64);
            part += __shfl_xor(part, 2, 64);            // all 4 kblock-lanes hold xn
            h8 hv;
#pragma unroll
            for (int i = 0; i < 8; ++i) hv[i] = (_Float16)x[i];
            if (gq == 3)                                // one lane per point: exact f32 xn + bias
                xnhb[s & 1][p] = fmaf(-0.5f, part, 64.f);
            // XOR-swizzled write slot: (p&15)^(gq<<2)
            unsigned char* dstb = convb[s & 1] + (p >> 4) * TILE_B + gq * 256
                                  + (((p & 15) ^ (gq << 2)) * 16);
            *(h8*)dstb = hv;
        }

        // ---- compute(s-1): hoisted bases + full unroll; 1 MFMA + med3 top-2 per (j,tile) ----
        if (s > 0) {
            int ss = s - 1;
            const unsigned char* cb = convb[ss & 1] + rdoff;    // single base per super-tile
            const float* xb = xnhb[ss & 1] + quad * 4;
            unsigned icb = 63u - (unsigned)(ss * NPT);          // ic = icb - t (SGPR)
            __builtin_amdgcn_s_setprio(1);
#pragma unroll
            for (int t = 0; t < NPT; ++t) {
                h8 ahi = *(const h8*)(cb + t * TILE_B);         // offset-immediate ds_read
                f4v xnh4 = *(const f4v*)(xb + t * 16);
                unsigned ic = icb - (unsigned)t;
#pragma unroll
                for (int j = 0; j < 2; ++j) {
                    f4v acc = __builtin_amdgcn_mfma_f32_16x16x32_f16(ahi, bhi[j], xnh4, 0, 0, 0);
#pragma unroll
                    for (int r = 0; r < 4; ++r) TRK(acc[r], ic, kb0[j][r], kb1[j][r]);
                }
            }
            __builtin_amdgcn_s_setprio(0);
        }
    }

    // epilogue: compute last super-tile
    __syncthreads();
    {
        int ss = NSUP - 1;
        const unsigned char* cb = convb[ss & 1] + rdoff;
        const float* xb = xnhb[ss & 1] + quad * 4;
        unsigned icb = 63u - (unsigned)(ss * NPT);
        __builtin_amdgcn_s_setprio(1);
#pragma unroll
        for (int t = 0; t < NPT; ++t) {
            h8 ahi = *(const h8*)(cb + t * TILE_B);
            f4v xnh4 = *(const f4v*)(xb + t * 16);
            unsigned ic = icb - (unsigned)t;
#pragma unroll
            for (int j = 0; j < 2; ++j) {
                f4v acc = __builtin_amdgcn_mfma_f32_16x16x32_f16(ahi, bhi[j], xnh4, 0, 0, 0);
#pragma unroll
                for (int r = 0; r < 4; ++r) TRK(acc[r], ic, kb0[j][r], kb1[j][r]);
            }
        }
        __builtin_amdgcn_s_setprio(0);
    }

    // decode + cross-quad merge (4 disjoint point subsets per query) -> block top-3
    // sort64 = (~(key|63) << 32) | gidx : ascending u64 == exact lex (quantized d, idx)
    int g = blockIdx.x;
    int qr4 = quad * 4;
#pragma unroll
    for (int j = 0; j < 2; ++j) {
        unsigned long long t0 = U64MAX, t1 = U64MAX, t2 = U64MAX;
#pragma unroll
        for (int r = 0; r < 4; ++r) {
#pragma unroll
            for (int h = 0; h < 2; ++h) {
                unsigned k = h ? kb1[j][r] : kb0[j][r];
                unsigned tile = 63u - (k & 63u);
                unsigned gi = (unsigned)(p0 + (int)tile * 16 + qr4 + r);
                unsigned long long e = ((unsigned long long)(~(k | 63u)) << 32) | gi;
                ins3u64(e, t0, t1, t2);
            }
        }
#pragma unroll
        for (int step = 16; step <= 32; step <<= 1) {
            unsigned long long o0 = shfl_xor_u64(t0, step);
            unsigned long long o1 = shfl_xor_u64(t1, step);
            unsigned long long o2 = shfl_xor_u64(t2, step);
            ins3u64(o0, t0, t1, t2);
            ins3u64(o1, t0, t1, t2);
            ins3u64(o2, t0, t1, t2);
        }
        if (quad == 0) {
            int qq = (w * 2 + j) * 16 + l15;
            size_t off = (size_t)qq * NC + (size_t)g * KNN;
            cand[off + 0] = t0; cand[off + 1] = t1; cand[off + 2] = t2;
        }
    }
}

// branchless compare-exchange (ascending)
#define CE(a, b) do { unsigned long long lo_ = (a) < (b) ? (a) : (b); \
                      unsigned long long hi_ = (a) < (b) ? (b) : (a); \
                      (a) = lo_; (b) = hi_; } while (0)

// ---------------- pass 2: parallel u64 top-8 merge -> exact f32 refine -> vote ----------------
__global__ __launch_bounds__(P2T) void k_pass2(const unsigned long long* __restrict__ cand,
                                               const float* __restrict__ train,
                                               const float* __restrict__ query,
                                               const unsigned* __restrict__ scale_u,
                                               const float* __restrict__ labels,
                                               float* __restrict__ out) {
    __shared__ unsigned long long smerge[64];   // 8 waves x top-8
    int q = blockIdx.x;
    int tid = threadIdx.x, lane = tid & 63, w = tid >> 6;
    const unsigned long long* cd = cand + (size_t)q * NC;

    // phase A: each thread owns <=3 candidates (1500 / 512); sort-3 (named regs, rule #20)
    unsigned long long c0 = cd[tid];
    unsigned long long c1 = cd[tid + P2T];
    unsigned long long c2 = (tid + 2 * P2T < NC) ? cd[tid + 2 * P2T] : U64MAX;
    CE(c0, c1); CE(c0, c2); CE(c1, c2);   // ascending

    // phase B: per-wave top-8 by repeated butterfly-u64-min extraction; lane 0 -> LDS
#pragma unroll
    for (int k = 0; k < 8; ++k) {
        unsigned long long m = c0;
#pragma unroll
        for (int st = 1; st < 64; st <<= 1) {
            unsigned long long o = shfl_xor_u64(m, st);
            if (o < m) m = o;
        }
        if (lane == 0) smerge[w * 8 + k] = m;
        bool win = (c0 == m);                 // exactly one lane (unique idx, m < U64MAX)
        c0 = win ? c1 : c0;
        c1 = win ? c2 : c1;
        c2 = win ? U64MAX : c2;
    }
    __syncthreads();
    if (w != 0) return;

    // phase C (wave 0): merge 8x8 wave winners -> global top-8; lane k keeps idx of rank k
    int myi = 0x7fffffff;
    {
        unsigned long long cur = smerge[lane];   // 64 real, unique entries
#pragma unroll
        for (int k = 0; k < 8; ++k) {
            unsigned long long m = cur;
#pragma unroll
            for (int st = 1; st < 64; st <<= 1) {
                unsigned long long o = shfl_xor_u64(m, st);
                if (o < m) m = o;
            }
            if (lane == k) myi = (int)(unsigned)m;
            if (cur == m) cur = U64MAX;
        }
    }

    // exact f32 scaled query + qn (same op order as the verified path)
    float inv[DIMS], qs_[DIMS], qn_ = 0.f;
#pragma unroll
    for (int d = 0; d < DIMS; ++d) {
        float sc = __uint_as_float(scale_u[d]);
        float iv = (sc != 0.f) ? 1.f / sc : 0.f;
        float v = query[(size_t)q * DIMS + d] * iv;
        inv[d] = iv; qs_[d] = v;
        qn_ = fmaf(v, v, qn_);
    }

    float myd2 = 3.4e38f;
    if (lane < 8) {
        const float* r = train + (size_t)myi * DIMS;
        float xnv = 0.f, dot = 0.f;
#pragma unroll
        for (int d = 0; d < DIMS; ++d) {
            float v = r[d] * inv[d];
            xnv = fmaf(v, v, xnv);
            dot = fmaf(qs_[d], v, dot);
        }
        myd2 = fmaf(-2.f, dot, qn_ + xnv);
    }

    float bd[KNN] = {3.4e38f, 3.4e38f, 3.4e38f};
    int   bi[KNN] = {0x7fffffff, 0x7fffffff, 0x7fffffff};
#pragma unroll
    for (int k = 0; k < 8; ++k) {
        float dk = __shfl(myd2, k, 64);
        int   ik = __shfl(myi, k, 64);
        insert3(dk, ik, bd, bi);
    }

    if (lane == 0) {
        float kd[KNN];
#pragma unroll
        for (int k = 0; k < KNN; ++k) kd[k] = sqrtf(fmaxf(bd[k], 0.f));
        float lab[KNN][NCLS];
#pragma unroll
        for (int k = 0; k < KNN; ++k) {
            const float* lr = labels + (size_t)bi[k] * NCLS;
#pragma unroll
            for (int c = 0; c < NCLS; ++c) lab[k][c] = lr[c];
        }
        float votes[NCLS];
#pragma unroll
        for (int c = 0; c < NCLS; ++c) votes[c] = 0.f;
#pragma unroll
        for (int k = 0; k < KNN; ++k) {
            float ks = (kd[k] == 0.f) ? 1.f : kd[k];
#pragma unroll
            for (int c = 0; c < NCLS; ++c) votes[c] += lab[k][c] / ks;
        }
        int best = 0; float bv = votes[0];
#pragma unroll
        for (int c = 1; c < NCLS; ++c) { if (votes[c] > bv) { bv = votes[c]; best = c; } }
        bool zero_hit = (kd[0] == 0.f);
#pragma unroll
        for (int k = 0; k < KNN; ++k) out[(size_t)q * KNN + k] = kd[k];
        float* ro = out + (size_t)BQ * KNN + (size_t)q * NCLS;
#pragma unroll
        for (int c = 0; c < NCLS; ++c)
            ro[c] = zero_hit ? lab[0][c] : ((c == best) ? 1.f : 0.f);
    }
}

extern "C" void kernel_launch(void* const* d_in, const int* in_sizes, int n_in,
                              void* d_out, int out_size, void* d_ws, size_t ws_size,
                              hipStream_t stream) {
    const float* query  = (const float*)d_in[0];
    const float* train  = (const float*)d_in[1];
    const float* labels = (const float*)d_in[2];
    float* out = (float*)d_out;

    // ws layout:
    //   [0)       scale_u: 32 u32 (128 B)
    //   [128)     Qhi: 512*32 f16 (32768 B)
    //   [32896)   cand: 512*1500 u64 (6144000 B)   total ~6.2 MB
    char* ws = (char*)d_ws;
    unsigned*  scale_u = (unsigned*)ws;
    _Float16*  Qhi = (_Float16*)(ws + 128);
    unsigned long long* cand = (unsigned long long*)(ws + 32896);

    hipMemsetAsync(ws, 0, 128, stream);  // zero scale accumulators
    k_scale<<<SCB, 256, 0, stream>>>(train, scale_u);
    k_qprep<<<8, 64, 0, stream>>>(query, scale_u, Qhi);
    k_pass1<<<NB, P1T, 0, stream>>>(train, scale_u, Qhi, cand);
    k_pass2<<<BQ, P2T, 0, stream>>>(cand, train, query, scale_u, labels, out);
}